// Round 1
// baseline (2391.239 us; speedup 1.0000x reference)
//
#include <hip/hip_runtime.h>
#include <hip/hip_bf16.h>
#include <math.h>

#define NN 24576
#define NE 98304
#define ETOT (NE + NN)
#define NG 512
#define NB 512
#define LL 1000
#define TL 64

__device__ inline void atomicMaxFloat(float* addr, float val) {
    int* ai = (int*)addr;
    int old = __float_as_int(*addr);
    while (__int_as_float(old) < val) {
        int assumed = old;
        old = atomicCAS(ai, assumed, __float_as_int(val));
        if (old == assumed) break;
    }
}

// ---------------- init ----------------
__global__ void k_init(float* m1, float* den1, float* acc1,
                       float* m2, float* den2, float* acc2,
                       float* sums, float* cnt, float* pmax) {
    int i = blockIdx.x * 256 + threadIdx.x;
    if (i < NN * 128) { acc1[i] = 0.f; acc2[i] = 0.f; }
    if (i < NN * 2) { m1[i] = -1e30f; den1[i] = 0.f; }
    if (i < NN) { m2[i] = -1e30f; den2[i] = 0.f; }
    if (i < NG * 128) sums[i] = 0.f;
    if (i < NG) cnt[i] = 0.f;
    if (i < NB * 128) pmax[i] = -1e30f;
}

// ---------------- weight transposes for conv ----------------
__global__ void k_prep_w(const float* K1, const float* K2, float* K1t, float* K2t) {
    int idx = blockIdx.x * 256 + threadIdx.x;
    if (idx < 64 * 64 * 3) {          // K1 [o][i][k] -> K1t[k][i][o]
        int o = idx / 192, r = idx % 192, i = r / 3, k = r % 3;
        K1t[(k * 64 + i) * 64 + o] = K1[idx];
    }
    if (idx < 128 * 64 * 5) {         // K2 [o][i][k] -> K2t[k][i][o]
        int o = idx / 320, r = idx % 320, i = r / 5, k = r % 5;
        K2t[(k * 64 + i) * 128 + o] = K2[idx];
    }
}

// ---------------- GAT layer 1: h = x@W1, a_s/a_d dot ----------------
__global__ void k_gat1_hatt(const float* x, const float* W1, const float* asrc, const float* adst,
                            float* h1, float* as_, float* ad_) {
    int n = blockIdx.x, j = threadIdx.x;   // 128 threads
    __shared__ float xs[5];
    if (j < 5) xs[j] = x[n * 5 + j];
    __syncthreads();
    float acc = 0.f;
#pragma unroll
    for (int f = 0; f < 5; f++) acc += xs[f] * W1[f * 128 + j];
    h1[n * 128 + j] = acc;
    int hd = j >> 6, c = j & 63;
    float ps = acc * asrc[hd * 64 + c];
    float pd = acc * adst[hd * 64 + c];
    for (int off = 32; off > 0; off >>= 1) {
        ps += __shfl_down(ps, off, 64);
        pd += __shfl_down(pd, off, 64);
    }
    if (c == 0) { as_[n * 2 + hd] = ps; ad_[n * 2 + hd] = pd; }
}

// ---------------- GAT layer 2: h = g@W2 (K=128), a_s/a_d ----------------
__global__ void k_gat2_hatt(const float* g1, const float* W2, const float* asrc, const float* adst,
                            float* h2, float* as_, float* ad_) {
    int n = blockIdx.x, j = threadIdx.x;   // 128 threads
    __shared__ float row[128];
    __shared__ float red[4];
    row[j] = g1[n * 128 + j];
    __syncthreads();
    float acc = 0.f;
#pragma unroll 8
    for (int c = 0; c < 128; c++) acc += row[c] * W2[c * 128 + j];
    h2[n * 128 + j] = acc;
    float ps = acc * asrc[j], pd = acc * adst[j];
    for (int off = 32; off > 0; off >>= 1) {
        ps += __shfl_down(ps, off, 64);
        pd += __shfl_down(pd, off, 64);
    }
    int lane = j & 63, wv = j >> 6;
    if (lane == 0) { red[wv * 2] = ps; red[wv * 2 + 1] = pd; }
    __syncthreads();
    if (j == 0) { as_[n] = red[0] + red[2]; ad_[n] = red[1] + red[3]; }
}

// ---------------- edge pass 1: e = lrelu(as[src]+ad[dst]); segment max ----------------
template <int H>
__global__ void k_edge_max(const int* ei, const float* as_, const float* ad_, float* e, float* m) {
    int idx = blockIdx.x * 256 + threadIdx.x;
    if (idx >= ETOT * H) return;
    int eid = idx / H, hd = idx % H;
    int s, d;
    if (eid < NE) { s = ei[eid]; d = ei[NE + eid]; }
    else { s = d = eid - NE; }
    float v = as_[s * H + hd] + ad_[d * H + hd];
    v = v >= 0.f ? v : 0.2f * v;
    e[idx] = v;
    atomicMaxFloat(&m[d * H + hd], v);
}

// ---------------- edge pass 2: w = exp(e-m[dst]); den += w ----------------
template <int H>
__global__ void k_edge_w(const int* ei, const float* m, float* e, float* den) {
    int idx = blockIdx.x * 256 + threadIdx.x;
    if (idx >= ETOT * H) return;
    int eid = idx / H, hd = idx % H;
    int d;
    if (eid < NE) d = ei[NE + eid];
    else d = eid - NE;
    float w = expf(e[idx] - m[d * H + hd]);
    e[idx] = w;
    atomicAdd(&den[d * H + hd], w);
}

// ---------------- edge pass 3: acc[dst] += w * h[src] ----------------
template <int H>
__global__ void k_edge_acc(const int* ei, const float* w, const float* h, float* acc) {
    int idx = blockIdx.x * 256 + threadIdx.x;   // ETOT*128
    int eid = idx >> 7, j = idx & 127;
    if (eid >= ETOT) return;
    int hd = (H == 2) ? (j >> 6) : 0;
    int s, d;
    if (eid < NE) { s = ei[eid]; d = ei[NE + eid]; }
    else { s = d = eid - NE; }
    atomicAdd(&acc[d * 128 + j], w[eid * H + hd] * h[s * 128 + j]);
}

// ---------------- finalize: g = elu(acc/(den+eps) + b) ----------------
template <int H>
__global__ void k_gat_fin(const float* acc, const float* den, const float* b, float* g) {
    int idx = blockIdx.x * 256 + threadIdx.x;   // NN*128
    if (idx >= NN * 128) return;
    int n = idx >> 7, j = idx & 127;
    int hd = (H == 2) ? (j >> 6) : 0;
    float v = acc[idx] / (den[n * H + hd] + 1e-16f) + b[j];
    g[idx] = v > 0.f ? v : expm1f(v);
}

// ---------------- mean pool over batch ----------------
__global__ void k_pool(const float* g2, const int* batch, float* sums, float* cnt) {
    int idx = blockIdx.x * 256 + threadIdx.x;   // NN*128
    if (idx >= NN * 128) return;
    int n = idx >> 7, j = idx & 127;
    int b = batch[n];
    atomicAdd(&sums[b * 128 + j], g2[idx]);
    if (j == 0) atomicAdd(&cnt[b], 1.f);
}

// ---------------- drug FC: relu(mean @ Wd + bd) ----------------
__global__ void k_drug_fc(const float* sums, const float* cnt, const float* Wd, const float* bd,
                          float* drug) {
    int idx = blockIdx.x * 256 + threadIdx.x;   // NG*256
    if (idx >= NG * 256) return;
    int g = idx >> 8, o = idx & 255;
    float c = cnt[g]; c = c < 1.f ? 1.f : c;
    float inv = 1.f / c;
    float acc = bd[o];
#pragma unroll 8
    for (int i = 0; i < 128; i++) acc += sums[g * 128 + i] * inv * Wd[i * 256 + o];
    drug[idx] = acc > 0.f ? acc : 0.f;
}

// ---------------- fused protein: embed -> conv1 -> conv2 -> maxpool ----------------
__global__ __launch_bounds__(256, 2) void k_protein(
    const int* seq, const float* Pe, const float* K1t, const float* bk1,
    const float* K2t, const float* bk2, float* pmax) {
    __shared__ float sPe[22 * 64];        // 5.5 KB
    __shared__ int sIdx[TL + 6];          // 70 entries
    __shared__ float s1[TL + 4][64];      // 17.4 KB conv1 out (channel-last)
    __shared__ float k2s[64 * 128];       // 32 KB one conv2 tap

    int b = blockIdx.x >> 4;
    int tile = blockIdx.x & 15;
    int t0 = tile * TL;
    int t = threadIdx.x;

    for (int i = t; i < 22 * 64; i += 256) sPe[i] = Pe[i];
    if (t < TL + 6) {
        int le = t0 - 3 + t;
        sIdx[t] = (le >= 0 && le < LL) ? seq[b * LL + le] : -1;
    }
    __syncthreads();

    // ---- conv1: s1[q][o] for q in [0,68), l = t0-2+q ----
    {
        int o = t & 63, qb = t >> 6;      // qb in [0,4), 17 positions each
        float acc[17];
#pragma unroll
        for (int j = 0; j < 17; j++) acc[j] = bk1[o];
        for (int kk = 0; kk < 3; kk++) {
            for (int i = 0; i < 64; i += 4) {
                float w0 = K1t[(kk * 64 + i + 0) * 64 + o];
                float w1 = K1t[(kk * 64 + i + 1) * 64 + o];
                float w2 = K1t[(kk * 64 + i + 2) * 64 + o];
                float w3 = K1t[(kk * 64 + i + 3) * 64 + o];
#pragma unroll
                for (int j = 0; j < 17; j++) {
                    int q = qb * 17 + j;
                    int id = sIdx[q + kk];
                    if (id >= 0) {
                        const float* pe = &sPe[id * 64 + i];
                        acc[j] += pe[0] * w0 + pe[1] * w1 + pe[2] * w2 + pe[3] * w3;
                    }
                }
            }
        }
#pragma unroll
        for (int j = 0; j < 17; j++) {
            int q = qb * 17 + j;
            int l = t0 - 2 + q;
            float v = acc[j];
            v = v > 0.f ? v : expm1f(v);
            s1[q][o] = (l >= 0 && l < LL) ? v : 0.f;
        }
    }
    __syncthreads();

    // ---- conv2: positions p in [0,64), l = t0+p ----
    {
        int o2 = t & 127, half = t >> 7;  // half in {0,1}, 32 positions each
        float acc2[32];
#pragma unroll
        for (int j = 0; j < 32; j++) acc2[j] = bk2[o2];
        for (int kk = 0; kk < 5; kk++) {
            __syncthreads();
            for (int i2 = t; i2 < 64 * 128; i2 += 256) k2s[i2] = K2t[kk * 64 * 128 + i2];
            __syncthreads();
            for (int i = 0; i < 64; i += 4) {
                float w0 = k2s[(i + 0) * 128 + o2];
                float w1 = k2s[(i + 1) * 128 + o2];
                float w2 = k2s[(i + 2) * 128 + o2];
                float w3 = k2s[(i + 3) * 128 + o2];
#pragma unroll
                for (int j = 0; j < 32; j++) {
                    int p = half * 32 + j;
                    const float* sp = &s1[p + kk][i];
                    acc2[j] += sp[0] * w0 + sp[1] * w1 + sp[2] * w2 + sp[3] * w3;
                }
            }
        }
        float mx = -1e30f;
#pragma unroll
        for (int j = 0; j < 32; j++) {
            int p = half * 32 + j, l = t0 + p;
            float v = acc2[j];
            v = v > 0.f ? v : expm1f(v);
            if (l < LL) mx = fmaxf(mx, v);
        }
        atomicMaxFloat(&pmax[b * 128 + o2], mx);
    }
}

// ---------------- protein FC: relu(pmax @ Wp + bp) ----------------
__global__ void k_prot_fc(const float* pmax, const float* Wp, const float* bp, float* prot) {
    int idx = blockIdx.x * 256 + threadIdx.x;   // NB*256
    if (idx >= NB * 256) return;
    int g = idx >> 8, o = idx & 255;
    float acc = bp[o];
#pragma unroll 8
    for (int i = 0; i < 128; i++) acc += pmax[g * 128 + i] * Wp[i * 256 + o];
    prot[idx] = acc > 0.f ? acc : 0.f;
}

// ---------------- head MLP ----------------
__global__ void k_head(const float* drug, const float* prot, const float* Wf1, const float* bf1,
                       const float* Wf2, const float* bf2, const float* Wo, const float* bo,
                       float* out) {
    __shared__ float in[512];
    __shared__ float hh[128];
    __shared__ float h2s[64];
    int g = blockIdx.x, t = threadIdx.x;   // 128 threads
    in[t] = drug[g * 256 + t];
    in[128 + t] = drug[g * 256 + 128 + t];
    in[256 + t] = prot[g * 256 + t];
    in[384 + t] = prot[g * 256 + 128 + t];
    __syncthreads();
    float acc = bf1[t];
#pragma unroll 8
    for (int c = 0; c < 512; c++) acc += in[c] * Wf1[c * 128 + t];
    hh[t] = acc > 0.f ? acc : 0.f;
    __syncthreads();
    if (t < 64) {
        float a2 = bf2[t];
#pragma unroll 8
        for (int c = 0; c < 128; c++) a2 += hh[c] * Wf2[c * 64 + t];
        h2s[t] = a2 > 0.f ? a2 : 0.f;
    }
    __syncthreads();
    if (t == 0) {
        float o = bo[0];
#pragma unroll 8
        for (int c = 0; c < 64; c++) o += h2s[c] * Wo[c];
        out[g] = o;
    }
}

extern "C" void kernel_launch(void* const* d_in, const int* in_sizes, int n_in,
                              void* d_out, int out_size, void* d_ws, size_t ws_size,
                              hipStream_t stream) {
    (void)in_sizes; (void)n_in; (void)out_size; (void)ws_size;
    const float* x   = (const float*)d_in[0];
    const int* ei    = (const int*)d_in[1];
    const int* batch = (const int*)d_in[2];
    const int* seq   = (const int*)d_in[3];
    const float* W1  = (const float*)d_in[4];
    const float* a_s1 = (const float*)d_in[5];
    const float* a_d1 = (const float*)d_in[6];
    const float* b1  = (const float*)d_in[7];
    const float* W2  = (const float*)d_in[8];
    const float* a_s2 = (const float*)d_in[9];
    const float* a_d2 = (const float*)d_in[10];
    const float* b2  = (const float*)d_in[11];
    const float* Wd  = (const float*)d_in[12];
    const float* bd  = (const float*)d_in[13];
    const float* Pe  = (const float*)d_in[14];
    const float* K1  = (const float*)d_in[15];
    const float* bk1 = (const float*)d_in[16];
    const float* K2  = (const float*)d_in[17];
    const float* bk2 = (const float*)d_in[18];
    const float* Wp  = (const float*)d_in[19];
    const float* bp  = (const float*)d_in[20];
    const float* Wf1 = (const float*)d_in[21];
    const float* bf1 = (const float*)d_in[22];
    const float* Wf2 = (const float*)d_in[23];
    const float* bf2 = (const float*)d_in[24];
    const float* Wo  = (const float*)d_in[25];
    const float* bo  = (const float*)d_in[26];
    float* out = (float*)d_out;

    float* w = (float*)d_ws;
    float* h1   = w; w += NN * 128;
    float* g1   = w; w += NN * 128;
    float* h2   = w; w += NN * 128;
    float* g2   = w; w += NN * 128;
    float* acc1 = w; w += NN * 128;
    float* acc2 = w; w += NN * 128;
    float* as1  = w; w += NN * 2;
    float* ad1  = w; w += NN * 2;
    float* m1   = w; w += NN * 2;
    float* den1 = w; w += NN * 2;
    float* as2  = w; w += NN;
    float* ad2  = w; w += NN;
    float* m2   = w; w += NN;
    float* den2 = w; w += NN;
    float* e1   = w; w += ETOT * 2;
    float* e2   = w; w += ETOT;
    float* sums = w; w += NG * 128;
    float* cnt  = w; w += NG;
    float* drug = w; w += NG * 256;
    float* prot = w; w += NB * 256;
    float* pmax = w; w += NB * 128;
    float* K1t  = w; w += 64 * 64 * 3;
    float* K2t  = w; w += 128 * 64 * 5;

    hipLaunchKernelGGL(k_init, dim3(NN * 128 / 256), dim3(256), 0, stream,
                       m1, den1, acc1, m2, den2, acc2, sums, cnt, pmax);
    hipLaunchKernelGGL(k_prep_w, dim3((128 * 64 * 5 + 255) / 256), dim3(256), 0, stream,
                       K1, K2, K1t, K2t);

    // ---- protein branch (independent; heavy) ----
    hipLaunchKernelGGL(k_protein, dim3(NB * 16), dim3(256), 0, stream,
                       seq, Pe, K1t, bk1, K2t, bk2, pmax);
    hipLaunchKernelGGL(k_prot_fc, dim3(NB * 256 / 256), dim3(256), 0, stream,
                       pmax, Wp, bp, prot);

    // ---- GAT layer 1 ----
    hipLaunchKernelGGL(k_gat1_hatt, dim3(NN), dim3(128), 0, stream,
                       x, W1, a_s1, a_d1, h1, as1, ad1);
    hipLaunchKernelGGL(k_edge_max<2>, dim3((ETOT * 2 + 255) / 256), dim3(256), 0, stream,
                       ei, as1, ad1, e1, m1);
    hipLaunchKernelGGL(k_edge_w<2>, dim3((ETOT * 2 + 255) / 256), dim3(256), 0, stream,
                       ei, m1, e1, den1);
    hipLaunchKernelGGL(k_edge_acc<2>, dim3(ETOT * 128 / 256), dim3(256), 0, stream,
                       ei, e1, h1, acc1);
    hipLaunchKernelGGL(k_gat_fin<2>, dim3(NN * 128 / 256), dim3(256), 0, stream,
                       acc1, den1, b1, g1);

    // ---- GAT layer 2 ----
    hipLaunchKernelGGL(k_gat2_hatt, dim3(NN), dim3(128), 0, stream,
                       g1, W2, a_s2, a_d2, h2, as2, ad2);
    hipLaunchKernelGGL(k_edge_max<1>, dim3((ETOT + 255) / 256), dim3(256), 0, stream,
                       ei, as2, ad2, e2, m2);
    hipLaunchKernelGGL(k_edge_w<1>, dim3((ETOT + 255) / 256), dim3(256), 0, stream,
                       ei, m2, e2, den2);
    hipLaunchKernelGGL(k_edge_acc<1>, dim3(ETOT * 128 / 256), dim3(256), 0, stream,
                       ei, e2, h2, acc2);
    hipLaunchKernelGGL(k_gat_fin<1>, dim3(NN * 128 / 256), dim3(256), 0, stream,
                       acc2, den2, b2, g2);

    // ---- pool + drug FC ----
    hipLaunchKernelGGL(k_pool, dim3(NN * 128 / 256), dim3(256), 0, stream,
                       g2, batch, sums, cnt);
    hipLaunchKernelGGL(k_drug_fc, dim3(NG * 256 / 256), dim3(256), 0, stream,
                       sums, cnt, Wd, bd, drug);

    // ---- head ----
    hipLaunchKernelGGL(k_head, dim3(NG), dim3(128), 0, stream,
                       drug, prot, Wf1, bf1, Wf2, bf2, Wo, bo, out);
}

// Round 3
// 666.276 us; speedup vs baseline: 3.5890x; 3.5890x over previous
//
#include <hip/hip_runtime.h>
#include <hip/hip_bf16.h>
#include <math.h>

#define NN 24576
#define NE 98304
#define ETOT (NE + NN)
#define NG 512
#define NB 512
#define LL 1000
#define TL 64

typedef __attribute__((ext_vector_type(8))) short short8;
typedef __attribute__((ext_vector_type(4))) float f32x4;

__device__ inline short f2bf(float x) {
    union { __hip_bfloat16 b; short s; } u;
    u.b = __float2bfloat16(x);
    return u.s;
}

__device__ inline void atomicMaxFloat(float* addr, float val) {
    int* ai = (int*)addr;
    int old = __float_as_int(*addr);
    while (__int_as_float(old) < val) {
        int assumed = old;
        old = atomicCAS(ai, assumed, __float_as_int(val));
        if (old == assumed) break;
    }
}

// ---------------- init ----------------
__global__ void k_init(float* m1, float* den1, float* acc1,
                       float* m2, float* den2, float* acc2,
                       float* sums, float* cnt, float* pmax) {
    int i = blockIdx.x * 256 + threadIdx.x;
    if (i < NN * 128) { acc1[i] = 0.f; acc2[i] = 0.f; }
    if (i < NN * 2) { m1[i] = -1e30f; den1[i] = 0.f; }
    if (i < NN) { m2[i] = -1e30f; den2[i] = 0.f; }
    if (i < NG * 128) sums[i] = 0.f;
    if (i < NG) cnt[i] = 0.f;
    if (i < NB * 128) pmax[i] = -1e30f;
}

// ---------------- weight swizzle to MFMA B-fragment order (bf16) ----------------
// B-frag for mfma_f32_16x16x32_bf16: lane holds B[k=quad*8+j][n=lane&15], j in [0,8)
// Bswz[((kb*NT + nt)*64 + lane)*8 + j] = B[kb*32 + (lane>>4)*8 + j][nt*16 + (lane&15)]
__global__ void k_prep_w(const float* K1, const float* K2, short* Bswz1, short* Bswz2) {
    int idx = blockIdx.x * 256 + threadIdx.x;
    if (idx < 192 * 64) {       // B1: K=192 (6 kb), N=64 (4 nt)
        int j = idx & 7, lane = (idx >> 3) & 63, rest = idx >> 9;
        int nt = rest & 3, kb = rest >> 2;
        int k = kb * 32 + ((lane >> 4) << 3) + j;
        int n = nt * 16 + (lane & 15);
        int kk = k >> 6, i = k & 63;            // B1[k][n] = K1[n][i][kk], K1:(64,64,3)
        Bswz1[idx] = f2bf(K1[n * 192 + i * 3 + kk]);
    }
    if (idx < 320 * 128) {      // B2: K=320 (10 kb), N=128 (8 nt)
        int j = idx & 7, lane = (idx >> 3) & 63, rest = idx >> 9;
        int nt = rest & 7, kb = rest >> 3;
        int k = kb * 32 + ((lane >> 4) << 3) + j;
        int n = nt * 16 + (lane & 15);
        int kk = k / 64, i = k % 64;            // B2[k][n] = K2[n][i][kk], K2:(128,64,5)
        Bswz2[idx] = f2bf(K2[n * 320 + i * 5 + kk]);
    }
}

// ---------------- GAT layer 1: h = x@W1, a_s/a_d dot ----------------
__global__ void k_gat1_hatt(const float* x, const float* W1, const float* asrc, const float* adst,
                            float* h1, float* as_, float* ad_) {
    int n = blockIdx.x, j = threadIdx.x;   // 128 threads
    __shared__ float xs[5];
    if (j < 5) xs[j] = x[n * 5 + j];
    __syncthreads();
    float acc = 0.f;
#pragma unroll
    for (int f = 0; f < 5; f++) acc += xs[f] * W1[f * 128 + j];
    h1[n * 128 + j] = acc;
    int hd = j >> 6, c = j & 63;
    float ps = acc * asrc[hd * 64 + c];
    float pd = acc * adst[hd * 64 + c];
    for (int off = 32; off > 0; off >>= 1) {
        ps += __shfl_down(ps, off, 64);
        pd += __shfl_down(pd, off, 64);
    }
    if (c == 0) { as_[n * 2 + hd] = ps; ad_[n * 2 + hd] = pd; }
}

// ---------------- GAT layer 2: h = g@W2 (K=128), a_s/a_d ----------------
__global__ void k_gat2_hatt(const float* g1, const float* W2, const float* asrc, const float* adst,
                            float* h2, float* as_, float* ad_) {
    int n = blockIdx.x, j = threadIdx.x;   // 128 threads
    __shared__ float row[128];
    __shared__ float red[4];
    row[j] = g1[n * 128 + j];
    __syncthreads();
    float acc = 0.f;
#pragma unroll 8
    for (int c = 0; c < 128; c++) acc += row[c] * W2[c * 128 + j];
    h2[n * 128 + j] = acc;
    float ps = acc * asrc[j], pd = acc * adst[j];
    for (int off = 32; off > 0; off >>= 1) {
        ps += __shfl_down(ps, off, 64);
        pd += __shfl_down(pd, off, 64);
    }
    int lane = j & 63, wv = j >> 6;
    if (lane == 0) { red[wv * 2] = ps; red[wv * 2 + 1] = pd; }
    __syncthreads();
    if (j == 0) { as_[n] = red[0] + red[2]; ad_[n] = red[1] + red[3]; }
}

// ---------------- edge pass 1 ----------------
template <int H>
__global__ void k_edge_max(const int* ei, const float* as_, const float* ad_, float* e, float* m) {
    int idx = blockIdx.x * 256 + threadIdx.x;
    if (idx >= ETOT * H) return;
    int eid = idx / H, hd = idx % H;
    int s, d;
    if (eid < NE) { s = ei[eid]; d = ei[NE + eid]; }
    else { s = d = eid - NE; }
    float v = as_[s * H + hd] + ad_[d * H + hd];
    v = v >= 0.f ? v : 0.2f * v;
    e[idx] = v;
    atomicMaxFloat(&m[d * H + hd], v);
}

// ---------------- edge pass 2 ----------------
template <int H>
__global__ void k_edge_w(const int* ei, const float* m, float* e, float* den) {
    int idx = blockIdx.x * 256 + threadIdx.x;
    if (idx >= ETOT * H) return;
    int eid = idx / H, hd = idx % H;
    int d;
    if (eid < NE) d = ei[NE + eid];
    else d = eid - NE;
    float w = expf(e[idx] - m[d * H + hd]);
    e[idx] = w;
    atomicAdd(&den[d * H + hd], w);
}

// ---------------- edge pass 3 ----------------
template <int H>
__global__ void k_edge_acc(const int* ei, const float* w, const float* h, float* acc) {
    int idx = blockIdx.x * 256 + threadIdx.x;   // ETOT*128
    int eid = idx >> 7, j = idx & 127;
    if (eid >= ETOT) return;
    int hd = (H == 2) ? (j >> 6) : 0;
    int s, d;
    if (eid < NE) { s = ei[eid]; d = ei[NE + eid]; }
    else { s = d = eid - NE; }
    atomicAdd(&acc[d * 128 + j], w[eid * H + hd] * h[s * 128 + j]);
}

// ---------------- finalize ----------------
template <int H>
__global__ void k_gat_fin(const float* acc, const float* den, const float* b, float* g) {
    int idx = blockIdx.x * 256 + threadIdx.x;   // NN*128
    if (idx >= NN * 128) return;
    int n = idx >> 7, j = idx & 127;
    int hd = (H == 2) ? (j >> 6) : 0;
    float v = acc[idx] / (den[n * H + hd] + 1e-16f) + b[j];
    g[idx] = v > 0.f ? v : expm1f(v);
}

// ---------------- mean pool (sorted batch -> run-length local accumulate) ----------------
__global__ void k_pool(const float* g2, const int* batch, float* sums, float* cnt) {
    __shared__ int sb[96];
    int blk = blockIdx.x, j = threadIdx.x;
    int n0 = blk * 96;
    if (j < 96) sb[j] = batch[n0 + j];
    __syncthreads();
    int cur = sb[0], runStart = 0;
    float acc = 0.f;
    for (int q = 0; q < 96; q++) {
        int bb = sb[q];
        if (bb != cur) {
            atomicAdd(&sums[cur * 128 + j], acc);
            if (j == 0) atomicAdd(&cnt[cur], (float)(q - runStart));
            cur = bb; acc = 0.f; runStart = q;
        }
        acc += g2[(n0 + q) * 128 + j];
    }
    atomicAdd(&sums[cur * 128 + j], acc);
    if (j == 0) atomicAdd(&cnt[cur], (float)(96 - runStart));
}

// ---------------- drug FC ----------------
__global__ void k_drug_fc(const float* sums, const float* cnt, const float* Wd, const float* bd,
                          float* drug) {
    int idx = blockIdx.x * 256 + threadIdx.x;   // NG*256
    if (idx >= NG * 256) return;
    int g = idx >> 8, o = idx & 255;
    float c = cnt[g]; c = c < 1.f ? 1.f : c;
    float inv = 1.f / c;
    float acc = bd[o];
#pragma unroll 8
    for (int i = 0; i < 128; i++) acc += sums[g * 128 + i] * inv * Wd[i * 256 + o];
    drug[idx] = acc > 0.f ? acc : 0.f;
}

// ---------------- fused protein via MFMA bf16 ----------------
// Block: one (protein b, 64-pos tile). 256 thr = 4 waves.
// conv1 = GEMM [80pos x 192] x [192 x 64]; conv2 = GEMM [64pos x 320] x [320 x 128].
// im2col is free in *row* space: k = kk*64 + i -> LDS row (m + kk), channel chunk i.
// Each 8-elem MFMA chunk (multiple of 8) never crosses a 64-channel boundary, so
// with padded stride SSTR the read is sEmb[(m + koff/64)*SSTR + koff%64].
#define SSTR 72   // padded row stride (bf16): 144 B -> rows spread 4 banks apart
__global__ void k_protein(
    const int* seq, const float* Pe, const short* Bswz1, const float* bk1,
    const short* Bswz2, const float* bk2, float* pmax) {
    __shared__ __align__(16) short sEmb[82 * SSTR];  // row j = input pos t0-3+j, 11.8 KB
    __shared__ __align__(16) short s1[68 * SSTR];    // row q = conv1 out pos t0-2+q, 9.8 KB

    int b = blockIdx.x >> 4;
    int tile = blockIdx.x & 15;
    int t0 = tile * TL;
    int t = threadIdx.x;
    int wv = t >> 6, lane = t & 63;
    int ln15 = lane & 15, quad = lane >> 4;

    // ---- phase 0: gather embeddings (fp32 -> bf16), zero OOB rows ----
    // rows 0..69 are live conv1 inputs (pos t0-3 .. t0+66); rows 70..81 feed only
    // discarded outputs but must be initialized -> zero.
    for (int j0 = 0; j0 < 82; j0 += 64) {
        int j = j0 + (t >> 2);
        if (j < 82) {
            int c0 = (t & 3) * 16;
            int l = t0 - 3 + j;
            int id = (j < 70 && l >= 0 && l < LL) ? seq[b * LL + l] : -1;
            short* dst = &sEmb[j * SSTR + c0];
            if (id >= 0) {
                const float4* src = (const float4*)&Pe[id * 64 + c0];
#pragma unroll
                for (int v = 0; v < 4; v++) {
                    float4 f = src[v];
                    dst[v * 4 + 0] = f2bf(f.x);
                    dst[v * 4 + 1] = f2bf(f.y);
                    dst[v * 4 + 2] = f2bf(f.z);
                    dst[v * 4 + 3] = f2bf(f.w);
                }
            } else {
#pragma unroll
                for (int v = 0; v < 16; v++) dst[v] = 0;
            }
        }
    }
    __syncthreads();

    // ---- phase 1: conv1 GEMM. 20 tiles (5 M x 4 N); wave wv owns nt=wv ----
    for (int tl = wv; tl < 20; tl += 4) {
        int mt = tl >> 2, nt = tl & 3;
        int arow = mt * 16 + ln15;
        f32x4 acc = {0.f, 0.f, 0.f, 0.f};
#pragma unroll
        for (int kb = 0; kb < 6; kb++) {
            int koff = kb * 32 + quad * 8;
            int kk = koff >> 6, i0 = koff & 63;          // tap, channel
            short8 a = *(const short8*)&sEmb[(arow + kk) * SSTR + i0];
            short8 bb = *(const short8*)&Bswz1[((kb * 4 + nt) * 64 + lane) * 8];
            acc = __builtin_amdgcn_mfma_f32_16x16x32_bf16(a, bb, acc, 0, 0, 0);
        }
        int col = nt * 16 + ln15;
        float bias = bk1[col];
#pragma unroll
        for (int r = 0; r < 4; r++) {
            int grow = mt * 16 + quad * 4 + r;       // q index
            if (grow < 68) {
                int l = t0 - 2 + grow;
                float v = acc[r] + bias;
                v = v > 0.f ? v : expm1f(v);
                s1[grow * SSTR + col] = (l >= 0 && l < LL) ? f2bf(v) : (short)0;
            }
        }
    }
    __syncthreads();

    // ---- phase 2: conv2 GEMM. wave = one 16-pos M-tile x all 8 N-tiles ----
    f32x4 acc2[8];
#pragma unroll
    for (int nt = 0; nt < 8; nt++) acc2[nt] = (f32x4){0.f, 0.f, 0.f, 0.f};
    int arow2 = wv * 16 + ln15;
#pragma unroll 2
    for (int kb = 0; kb < 10; kb++) {
        int koff = kb * 32 + quad * 8;
        int kk = koff >> 6, i0 = koff & 63;              // tap, channel
        short8 a = *(const short8*)&s1[(arow2 + kk) * SSTR + i0];
#pragma unroll
        for (int nt = 0; nt < 8; nt++) {
            short8 bb = *(const short8*)&Bswz2[((kb * 8 + nt) * 64 + lane) * 8];
            acc2[nt] = __builtin_amdgcn_mfma_f32_16x16x32_bf16(a, bb, acc2[nt], 0, 0, 0);
        }
    }
    // ---- epilogue: bias, elu, masked max over positions, atomic into pmax ----
#pragma unroll
    for (int nt = 0; nt < 8; nt++) {
        int col = nt * 16 + ln15;
        float bias = bk2[col];
        float mx = -1e30f;
#pragma unroll
        for (int r = 0; r < 4; r++) {
            int p = wv * 16 + quad * 4 + r;
            int l = t0 + p;
            float v = acc2[nt][r] + bias;
            v = v > 0.f ? v : expm1f(v);
            if (l < LL) mx = fmaxf(mx, v);
        }
        mx = fmaxf(mx, __shfl_xor(mx, 16, 64));
        mx = fmaxf(mx, __shfl_xor(mx, 32, 64));
        if (quad == 0) atomicMaxFloat(&pmax[b * 128 + col], mx);
    }
}

// ---------------- protein FC ----------------
__global__ void k_prot_fc(const float* pmax, const float* Wp, const float* bp, float* prot) {
    int idx = blockIdx.x * 256 + threadIdx.x;   // NB*256
    if (idx >= NB * 256) return;
    int g = idx >> 8, o = idx & 255;
    float acc = bp[o];
#pragma unroll 8
    for (int i = 0; i < 128; i++) acc += pmax[g * 128 + i] * Wp[i * 256 + o];
    prot[idx] = acc > 0.f ? acc : 0.f;
}

// ---------------- head MLP ----------------
__global__ void k_head(const float* drug, const float* prot, const float* Wf1, const float* bf1,
                       const float* Wf2, const float* bf2, const float* Wo, const float* bo,
                       float* out) {
    __shared__ float in[512];
    __shared__ float hh[128];
    __shared__ float h2s[64];
    int g = blockIdx.x, t = threadIdx.x;   // 128 threads
    in[t] = drug[g * 256 + t];
    in[128 + t] = drug[g * 256 + 128 + t];
    in[256 + t] = prot[g * 256 + t];
    in[384 + t] = prot[g * 256 + 128 + t];
    __syncthreads();
    float acc = bf1[t];
#pragma unroll 8
    for (int c = 0; c < 512; c++) acc += in[c] * Wf1[c * 128 + t];
    hh[t] = acc > 0.f ? acc : 0.f;
    __syncthreads();
    if (t < 64) {
        float a2 = bf2[t];
#pragma unroll 8
        for (int c = 0; c < 128; c++) a2 += hh[c] * Wf2[c * 64 + t];
        h2s[t] = a2 > 0.f ? a2 : 0.f;
    }
    __syncthreads();
    if (t == 0) {
        float o = bo[0];
#pragma unroll 8
        for (int c = 0; c < 64; c++) o += h2s[c] * Wo[c];
        out[g] = o;
    }
}

extern "C" void kernel_launch(void* const* d_in, const int* in_sizes, int n_in,
                              void* d_out, int out_size, void* d_ws, size_t ws_size,
                              hipStream_t stream) {
    (void)in_sizes; (void)n_in; (void)out_size; (void)ws_size;
    const float* x   = (const float*)d_in[0];
    const int* ei    = (const int*)d_in[1];
    const int* batch = (const int*)d_in[2];
    const int* seq   = (const int*)d_in[3];
    const float* W1  = (const float*)d_in[4];
    const float* a_s1 = (const float*)d_in[5];
    const float* a_d1 = (const float*)d_in[6];
    const float* b1  = (const float*)d_in[7];
    const float* W2  = (const float*)d_in[8];
    const float* a_s2 = (const float*)d_in[9];
    const float* a_d2 = (const float*)d_in[10];
    const float* b2  = (const float*)d_in[11];
    const float* Wd  = (const float*)d_in[12];
    const float* bd  = (const float*)d_in[13];
    const float* Pe  = (const float*)d_in[14];
    const float* K1  = (const float*)d_in[15];
    const float* bk1 = (const float*)d_in[16];
    const float* K2  = (const float*)d_in[17];
    const float* bk2 = (const float*)d_in[18];
    const float* Wp  = (const float*)d_in[19];
    const float* bp  = (const float*)d_in[20];
    const float* Wf1 = (const float*)d_in[21];
    const float* bf1 = (const float*)d_in[22];
    const float* Wf2 = (const float*)d_in[23];
    const float* bf2 = (const float*)d_in[24];
    const float* Wo  = (const float*)d_in[25];
    const float* bo  = (const float*)d_in[26];
    float* out = (float*)d_out;

    float* w = (float*)d_ws;
    float* h1   = w; w += NN * 128;
    float* g1   = w; w += NN * 128;
    float* h2   = w; w += NN * 128;
    float* g2   = w; w += NN * 128;
    float* acc1 = w; w += NN * 128;
    float* acc2 = w; w += NN * 128;
    float* as1  = w; w += NN * 2;
    float* ad1  = w; w += NN * 2;
    float* m1   = w; w += NN * 2;
    float* den1 = w; w += NN * 2;
    float* as2  = w; w += NN;
    float* ad2  = w; w += NN;
    float* m2   = w; w += NN;
    float* den2 = w; w += NN;
    float* e1   = w; w += ETOT * 2;
    float* e2   = w; w += ETOT;
    float* sums = w; w += NG * 128;
    float* cnt  = w; w += NG;
    float* drug = w; w += NG * 256;
    float* prot = w; w += NB * 256;
    float* pmax = w; w += NB * 128;
    short* Bswz1 = (short*)w; w += 192 * 64 / 2;
    short* Bswz2 = (short*)w; w += 320 * 128 / 2;

    hipLaunchKernelGGL(k_init, dim3(NN * 128 / 256), dim3(256), 0, stream,
                       m1, den1, acc1, m2, den2, acc2, sums, cnt, pmax);
    hipLaunchKernelGGL(k_prep_w, dim3((320 * 128 + 255) / 256), dim3(256), 0, stream,
                       K1, K2, Bswz1, Bswz2);

    // ---- protein branch (MFMA) ----
    hipLaunchKernelGGL(k_protein, dim3(NB * 16), dim3(256), 0, stream,
                       seq, Pe, Bswz1, bk1, Bswz2, bk2, pmax);
    hipLaunchKernelGGL(k_prot_fc, dim3(NB * 256 / 256), dim3(256), 0, stream,
                       pmax, Wp, bp, prot);

    // ---- GAT layer 1 ----
    hipLaunchKernelGGL(k_gat1_hatt, dim3(NN), dim3(128), 0, stream,
                       x, W1, a_s1, a_d1, h1, as1, ad1);
    hipLaunchKernelGGL(k_edge_max<2>, dim3((ETOT * 2 + 255) / 256), dim3(256), 0, stream,
                       ei, as1, ad1, e1, m1);
    hipLaunchKernelGGL(k_edge_w<2>, dim3((ETOT * 2 + 255) / 256), dim3(256), 0, stream,
                       ei, m1, e1, den1);
    hipLaunchKernelGGL(k_edge_acc<2>, dim3(ETOT * 128 / 256), dim3(256), 0, stream,
                       ei, e1, h1, acc1);
    hipLaunchKernelGGL(k_gat_fin<2>, dim3(NN * 128 / 256), dim3(256), 0, stream,
                       acc1, den1, b1, g1);

    // ---- GAT layer 2 ----
    hipLaunchKernelGGL(k_gat2_hatt, dim3(NN), dim3(128), 0, stream,
                       g1, W2, a_s2, a_d2, h2, as2, ad2);
    hipLaunchKernelGGL(k_edge_max<1>, dim3((ETOT + 255) / 256), dim3(256), 0, stream,
                       ei, as2, ad2, e2, m2);
    hipLaunchKernelGGL(k_edge_w<1>, dim3((ETOT + 255) / 256), dim3(256), 0, stream,
                       ei, m2, e2, den2);
    hipLaunchKernelGGL(k_edge_acc<1>, dim3(ETOT * 128 / 256), dim3(256), 0, stream,
                       ei, e2, h2, acc2);
    hipLaunchKernelGGL(k_gat_fin<1>, dim3(NN * 128 / 256), dim3(256), 0, stream,
                       acc2, den2, b2, g2);

    // ---- pool + drug FC ----
    hipLaunchKernelGGL(k_pool, dim3(NN / 96), dim3(128), 0, stream,
                       g2, batch, sums, cnt);
    hipLaunchKernelGGL(k_drug_fc, dim3(NG * 256 / 256), dim3(256), 0, stream,
                       sums, cnt, Wd, bd, drug);

    // ---- head ----
    hipLaunchKernelGGL(k_head, dim3(NG), dim3(128), 0, stream,
                       drug, prot, Wf1, bf1, Wf2, bf2, Wo, bo, out);
}

// Round 4
// 475.652 us; speedup vs baseline: 5.0273x; 1.4008x over previous
//
#include <hip/hip_runtime.h>
#include <hip/hip_bf16.h>
#include <math.h>

#define NN 24576
#define NE 98304
#define ETOT (NE + NN)
#define NG 512
#define NB 512
#define LL 1000
#define TL 128

typedef __attribute__((ext_vector_type(8))) short short8;
typedef __attribute__((ext_vector_type(4))) short short4v;
typedef __attribute__((ext_vector_type(4))) float f32x4;

__device__ inline short f2bf(float x) {
    union { __hip_bfloat16 b; short s; } u;
    u.b = __float2bfloat16(x);
    return u.s;
}

__device__ inline void atomicMaxFloat(float* addr, float val) {
    int* ai = (int*)addr;
    int old = __float_as_int(*addr);
    while (__int_as_float(old) < val) {
        int assumed = old;
        old = atomicCAS(ai, assumed, __float_as_int(val));
        if (old == assumed) break;
    }
}

// ---------------- init (everything re-poisoned each launch) ----------------
__global__ void k_init(int* deg, int* cursor, float* sums, float* cnt, float* pmax) {
    int i = blockIdx.x * 256 + threadIdx.x;   // 65536 threads
    if (i < NN) { deg[i] = 0; cursor[i] = 0; }
    if (i < NG * 128) sums[i] = 0.f;
    if (i < NG) cnt[i] = 0.f;
    if (i < NB * 128) pmax[i] = -1e30f;
}

// ---------------- CSR build ----------------
__global__ void k_count(const int* ei, int* deg) {
    int e = blockIdx.x * 256 + threadIdx.x;   // ETOT
    if (e >= ETOT) return;
    int d = (e < NE) ? ei[NE + e] : e - NE;
    atomicAdd(&deg[d], 1);
}

__global__ void k_scan1(const int* deg, int* excl, int* part) {
    __shared__ int s[256];
    int b = blockIdx.x, t = threadIdx.x, i = b * 256 + t;
    int v = deg[i];
    s[t] = v;
    __syncthreads();
    for (int o = 1; o < 256; o <<= 1) {
        int x = (t >= o) ? s[t - o] : 0;
        __syncthreads();
        s[t] += x;
        __syncthreads();
    }
    excl[i] = s[t] - v;
    if (t == 255) part[b] = s[t];
}

__global__ void k_scan2(int* part) {   // 96 partials, 1 block
    __shared__ int s[96];
    int t = threadIdx.x;
    if (t < 96) s[t] = part[t];
    __syncthreads();
    if (t == 0) {
        int run = 0;
        for (int i = 0; i < 96; i++) { int v = s[i]; s[i] = run; run += v; }
    }
    __syncthreads();
    if (t < 96) part[t] = s[t];
}

__global__ void k_scan3(const int* excl, const int* part, int* rowptr) {
    int i = blockIdx.x * 256 + threadIdx.x;   // NN
    rowptr[i] = excl[i] + part[i >> 8];
    if (i == 0) rowptr[NN] = ETOT;
}

__global__ void k_scatter(const int* ei, const int* rowptr, int* cursor, int* colidx) {
    int e = blockIdx.x * 256 + threadIdx.x;   // ETOT
    if (e >= ETOT) return;
    int s, d;
    if (e < NE) { s = ei[e]; d = ei[NE + e]; }
    else { s = d = e - NE; }
    int pos = atomicAdd(&cursor[d], 1);
    colidx[rowptr[d] + pos] = s;
}

// ---------------- GAT layer 1: h = x@W1, a_s/a_d dot ----------------
__global__ void k_gat1_hatt(const float* x, const float* W1, const float* asrc, const float* adst,
                            float* h1, float* as_, float* ad_) {
    int n = blockIdx.x, j = threadIdx.x;   // 128 threads
    __shared__ float xs[5];
    if (j < 5) xs[j] = x[n * 5 + j];
    __syncthreads();
    float acc = 0.f;
#pragma unroll
    for (int f = 0; f < 5; f++) acc += xs[f] * W1[f * 128 + j];
    h1[n * 128 + j] = acc;
    int hd = j >> 6, c = j & 63;
    float ps = acc * asrc[hd * 64 + c];
    float pd = acc * adst[hd * 64 + c];
    for (int off = 32; off > 0; off >>= 1) {
        ps += __shfl_down(ps, off, 64);
        pd += __shfl_down(pd, off, 64);
    }
    if (c == 0) { as_[n * 2 + hd] = ps; ad_[n * 2 + hd] = pd; }
}

// ---------------- GAT layer 2: h = g@W2 (K=128), a_s/a_d ----------------
__global__ void k_gat2_hatt(const float* g1, const float* W2, const float* asrc, const float* adst,
                            float* h2, float* as_, float* ad_) {
    int n = blockIdx.x, j = threadIdx.x;   // 128 threads
    __shared__ float row[128];
    __shared__ float red[4];
    row[j] = g1[n * 128 + j];
    __syncthreads();
    float acc = 0.f;
#pragma unroll 8
    for (int c = 0; c < 128; c++) acc += row[c] * W2[c * 128 + j];
    h2[n * 128 + j] = acc;
    float ps = acc * asrc[j], pd = acc * adst[j];
    for (int off = 32; off > 0; off >>= 1) {
        ps += __shfl_down(ps, off, 64);
        pd += __shfl_down(pd, off, 64);
    }
    int lane = j & 63, wv = j >> 6;
    if (lane == 0) { red[wv * 2] = ps; red[wv * 2 + 1] = pd; }
    __syncthreads();
    if (j == 0) { as_[n] = red[0] + red[2]; ad_[n] = red[1] + red[3]; }
}

// ---------------- dst-centric GAT aggregation: online softmax, no atomics ----------------
template <int H>
__global__ void k_agg(const int* rowptr, const int* colidx, const float* h,
                      const float* as_, const float* ad_, const float* bias, float* g) {
    int t = threadIdx.x;
    int d = blockIdx.x * 2 + (t >> 7);   // 2 nodes / 256-thr block
    int j = t & 127;
    int hd = (H == 2) ? (j >> 6) : 0;
    float adv = ad_[d * H + hd];
    int p0 = rowptr[d], p1 = rowptr[d + 1];
    float m = -1e30f, den = 0.f, acc = 0.f;
    for (int p = p0; p < p1; p++) {
        int s = colidx[p];
        float hv = h[s * 128 + j];
        float e = as_[s * H + hd] + adv;
        e = e >= 0.f ? e : 0.2f * e;
        float nm = fmaxf(m, e);
        float sc = __expf(m - nm);
        float w = __expf(e - nm);
        den = den * sc + w;
        acc = acc * sc + w * hv;
        m = nm;
    }
    float v = acc / (den + 1e-16f) + bias[j];
    g[d * 128 + j] = v > 0.f ? v : __expf(v) - 1.f;
}

// ---------------- mean pool (sorted batch -> run-length local accumulate) ----------------
__global__ void k_pool(const float* g2, const int* batch, float* sums, float* cnt) {
    __shared__ int sb[96];
    int blk = blockIdx.x, j = threadIdx.x;
    int n0 = blk * 96;
    if (j < 96) sb[j] = batch[n0 + j];
    __syncthreads();
    int cur = sb[0], runStart = 0;
    float acc = 0.f;
    for (int q = 0; q < 96; q++) {
        int bb = sb[q];
        if (bb != cur) {
            atomicAdd(&sums[cur * 128 + j], acc);
            if (j == 0) atomicAdd(&cnt[cur], (float)(q - runStart));
            cur = bb; acc = 0.f; runStart = q;
        }
        acc += g2[(n0 + q) * 128 + j];
    }
    atomicAdd(&sums[cur * 128 + j], acc);
    if (j == 0) atomicAdd(&cnt[cur], (float)(96 - runStart));
}

// ---------------- drug FC ----------------
__global__ void k_drug_fc(const float* sums, const float* cnt, const float* Wd, const float* bd,
                          float* drug) {
    int idx = blockIdx.x * 256 + threadIdx.x;   // NG*256
    if (idx >= NG * 256) return;
    int g = idx >> 8, o = idx & 255;
    float c = cnt[g]; c = c < 1.f ? 1.f : c;
    float inv = 1.f / c;
    float acc = bd[o];
#pragma unroll 8
    for (int i = 0; i < 128; i++) acc += sums[g * 128 + i] * inv * Wd[i * 256 + o];
    drug[idx] = acc > 0.f ? acc : 0.f;
}

// ---------------- weight swizzle to MFMA B-fragment order (bf16) ----------------
__global__ void k_prep_w(const float* K1, const float* K2, short* Bswz1, short* Bswz2) {
    int idx = blockIdx.x * 256 + threadIdx.x;
    if (idx < 192 * 64) {       // B1: K=192 (6 kb), N=64 (4 nt)
        int j = idx & 7, lane = (idx >> 3) & 63, rest = idx >> 9;
        int nt = rest & 3, kb = rest >> 2;
        int k = kb * 32 + ((lane >> 4) << 3) + j;
        int n = nt * 16 + (lane & 15);
        int kk = k >> 6, i = k & 63;            // B1[k][n] = K1[n][i][kk]
        Bswz1[idx] = f2bf(K1[n * 192 + i * 3 + kk]);
    }
    if (idx < 320 * 128) {      // B2: K=320 (10 kb), N=128 (8 nt)
        int j = idx & 7, lane = (idx >> 3) & 63, rest = idx >> 9;
        int nt = rest & 7, kb = rest >> 3;
        int k = kb * 32 + ((lane >> 4) << 3) + j;
        int n = nt * 16 + (lane & 15);
        int kk = k / 64, i = k % 64;            // B2[k][n] = K2[n][i][kk]
        Bswz2[idx] = f2bf(K2[n * 320 + i * 5 + kk]);
    }
}

// ---------------- fused protein via MFMA bf16, TL=128 ----------------
// conv1: M rows q (pos t0-2+q), q live < 132; M-tile starts {0,16,..,112,116} (last overlaps).
// conv2: M = 128 positions (8 tiles, 2 per wave with B-register reuse), N=128, K=320.
#define SSTR 72   // row stride (bf16) = 144 B: 16B-aligned rows, 2-way-free bank pattern
__global__ __launch_bounds__(256, 4) void k_protein(
    const int* seq, const float* Pe, const short* Bswz1, const float* bk1,
    const short* Bswz2, const float* bk2, float* pmax) {
    __shared__ __align__(16) short sEmb[134 * SSTR];  // row j = input pos t0-3+j, 18.8 KB
    __shared__ __align__(16) short s1[132 * SSTR];    // row q = conv1 out pos t0-2+q, 19.0 KB

    int b = blockIdx.x >> 3;
    int tile = blockIdx.x & 7;
    int t0 = tile * TL;
    int t = threadIdx.x;
    int wv = t >> 6, lane = t & 63;
    int ln15 = lane & 15, quad = lane >> 4;

    // ---- phase 0: gather embeddings (fp32 -> bf16), zero OOB rows ----
    for (int j0 = 0; j0 < 134; j0 += 64) {
        int j = j0 + (t >> 2);
        if (j < 134) {
            int c0 = (t & 3) * 16;
            int l = t0 - 3 + j;
            int id = (l >= 0 && l < LL) ? seq[b * LL + l] : -1;
            short* dst = &sEmb[j * SSTR + c0];
            if (id >= 0) {
                const float4* src = (const float4*)&Pe[id * 64 + c0];
#pragma unroll
                for (int v = 0; v < 4; v++) {
                    float4 f = src[v];
                    short4v o;
                    o.x = f2bf(f.x); o.y = f2bf(f.y); o.z = f2bf(f.z); o.w = f2bf(f.w);
                    *(short4v*)(dst + v * 4) = o;
                }
            } else {
#pragma unroll
                for (int v = 0; v < 4; v++) *(short4v*)(dst + v * 4) = (short4v){0, 0, 0, 0};
            }
        }
    }
    __syncthreads();

    // ---- phase 1: conv1. wave wv owns nt=wv (cols wv*16..); B preloaded in regs ----
    {
        short8 b1f[6];
#pragma unroll
        for (int kb = 0; kb < 6; kb++)
            b1f[kb] = *(const short8*)&Bswz1[((kb * 4 + wv) * 64 + lane) * 8];
        int col = wv * 16 + ln15;
        float bias = bk1[col];
        const int M0[9] = {0, 16, 32, 48, 64, 80, 96, 112, 116};
#pragma unroll
        for (int mi = 0; mi < 9; mi++) {
            int arow = M0[mi] + ln15;
            f32x4 acc = {0.f, 0.f, 0.f, 0.f};
#pragma unroll
            for (int kb = 0; kb < 6; kb++) {
                int koff = kb * 32 + quad * 8;
                int kk = koff >> 6, i0 = koff & 63;
                short8 a = *(const short8*)&sEmb[(arow + kk) * SSTR + i0];
                acc = __builtin_amdgcn_mfma_f32_16x16x32_bf16(a, b1f[kb], acc, 0, 0, 0);
            }
#pragma unroll
            for (int r = 0; r < 4; r++) {
                int q = M0[mi] + quad * 4 + r;
                if (q < 132) {
                    int l = t0 - 2 + q;
                    float v = acc[r] + bias;
                    v = v > 0.f ? v : __expf(v) - 1.f;
                    s1[q * SSTR + col] = (l >= 0 && l < LL) ? f2bf(v) : (short)0;
                }
            }
        }
    }
    __syncthreads();

    // ---- phase 2: conv2. wave = 2 M-tiles (2wv, 2wv+1) x 8 N-tiles; B reused x2 ----
    f32x4 acc2[2][8];
#pragma unroll
    for (int i = 0; i < 2; i++)
#pragma unroll
        for (int nt = 0; nt < 8; nt++) acc2[i][nt] = (f32x4){0.f, 0.f, 0.f, 0.f};
    int ar0 = (2 * wv) * 16 + ln15;
    int ar1 = (2 * wv + 1) * 16 + ln15;
#pragma unroll 2
    for (int kb = 0; kb < 10; kb++) {
        int koff = kb * 32 + quad * 8;
        int kk = koff >> 6, i0 = koff & 63;
        short8 a0 = *(const short8*)&s1[(ar0 + kk) * SSTR + i0];
        short8 a1 = *(const short8*)&s1[(ar1 + kk) * SSTR + i0];
#pragma unroll
        for (int nt = 0; nt < 8; nt++) {
            short8 bb = *(const short8*)&Bswz2[((kb * 8 + nt) * 64 + lane) * 8];
            acc2[0][nt] = __builtin_amdgcn_mfma_f32_16x16x32_bf16(a0, bb, acc2[0][nt], 0, 0, 0);
            acc2[1][nt] = __builtin_amdgcn_mfma_f32_16x16x32_bf16(a1, bb, acc2[1][nt], 0, 0, 0);
        }
    }
    // ---- epilogue: bias, elu, masked max over 32 rows, one atomic per (lane16, nt) ----
#pragma unroll
    for (int nt = 0; nt < 8; nt++) {
        int col = nt * 16 + ln15;
        float bias = bk2[col];
        float mx = -1e30f;
#pragma unroll
        for (int i = 0; i < 2; i++) {
#pragma unroll
            for (int r = 0; r < 4; r++) {
                int p = (2 * wv + i) * 16 + quad * 4 + r;
                int l = t0 + p;
                float v = acc2[i][nt][r] + bias;
                v = v > 0.f ? v : __expf(v) - 1.f;
                if (l < LL) mx = fmaxf(mx, v);
            }
        }
        mx = fmaxf(mx, __shfl_xor(mx, 16, 64));
        mx = fmaxf(mx, __shfl_xor(mx, 32, 64));
        if (quad == 0) atomicMaxFloat(&pmax[b * 128 + col], mx);
    }
}

// ---------------- protein FC ----------------
__global__ void k_prot_fc(const float* pmax, const float* Wp, const float* bp, float* prot) {
    int idx = blockIdx.x * 256 + threadIdx.x;   // NB*256
    if (idx >= NB * 256) return;
    int g = idx >> 8, o = idx & 255;
    float acc = bp[o];
#pragma unroll 8
    for (int i = 0; i < 128; i++) acc += pmax[g * 128 + i] * Wp[i * 256 + o];
    prot[idx] = acc > 0.f ? acc : 0.f;
}

// ---------------- head MLP ----------------
__global__ void k_head(const float* drug, const float* prot, const float* Wf1, const float* bf1,
                       const float* Wf2, const float* bf2, const float* Wo, const float* bo,
                       float* out) {
    __shared__ float in[512];
    __shared__ float hh[128];
    __shared__ float h2s[64];
    int g = blockIdx.x, t = threadIdx.x;   // 128 threads
    in[t] = drug[g * 256 + t];
    in[128 + t] = drug[g * 256 + 128 + t];
    in[256 + t] = prot[g * 256 + t];
    in[384 + t] = prot[g * 256 + 128 + t];
    __syncthreads();
    float acc = bf1[t];
#pragma unroll 8
    for (int c = 0; c < 512; c++) acc += in[c] * Wf1[c * 128 + t];
    hh[t] = acc > 0.f ? acc : 0.f;
    __syncthreads();
    if (t < 64) {
        float a2 = bf2[t];
#pragma unroll 8
        for (int c = 0; c < 128; c++) a2 += hh[c] * Wf2[c * 64 + t];
        h2s[t] = a2 > 0.f ? a2 : 0.f;
    }
    __syncthreads();
    if (t == 0) {
        float o = bo[0];
#pragma unroll 8
        for (int c = 0; c < 64; c++) o += h2s[c] * Wo[c];
        out[g] = o;
    }
}

extern "C" void kernel_launch(void* const* d_in, const int* in_sizes, int n_in,
                              void* d_out, int out_size, void* d_ws, size_t ws_size,
                              hipStream_t stream) {
    (void)in_sizes; (void)n_in; (void)out_size; (void)ws_size;
    const float* x   = (const float*)d_in[0];
    const int* ei    = (const int*)d_in[1];
    const int* batch = (const int*)d_in[2];
    const int* seq   = (const int*)d_in[3];
    const float* W1  = (const float*)d_in[4];
    const float* a_s1 = (const float*)d_in[5];
    const float* a_d1 = (const float*)d_in[6];
    const float* b1  = (const float*)d_in[7];
    const float* W2  = (const float*)d_in[8];
    const float* a_s2 = (const float*)d_in[9];
    const float* a_d2 = (const float*)d_in[10];
    const float* b2  = (const float*)d_in[11];
    const float* Wd  = (const float*)d_in[12];
    const float* bd  = (const float*)d_in[13];
    const float* Pe  = (const float*)d_in[14];
    const float* K1  = (const float*)d_in[15];
    const float* bk1 = (const float*)d_in[16];
    const float* K2  = (const float*)d_in[17];
    const float* bk2 = (const float*)d_in[18];
    const float* Wp  = (const float*)d_in[19];
    const float* bp  = (const float*)d_in[20];
    const float* Wf1 = (const float*)d_in[21];
    const float* bf1 = (const float*)d_in[22];
    const float* Wf2 = (const float*)d_in[23];
    const float* bf2 = (const float*)d_in[24];
    const float* Wo  = (const float*)d_in[25];
    const float* bo  = (const float*)d_in[26];
    float* out = (float*)d_out;

    float* w = (float*)d_ws;
    float* h1   = w; w += NN * 128;
    float* g1   = w; w += NN * 128;
    float* h2   = w; w += NN * 128;
    float* g2   = w; w += NN * 128;
    float* as1  = w; w += NN * 2;
    float* ad1  = w; w += NN * 2;
    float* as2  = w; w += NN;
    float* ad2  = w; w += NN;
    float* sums = w; w += NG * 128;
    float* cnt  = w; w += NG;
    float* drug = w; w += NG * 256;
    float* prot = w; w += NB * 256;
    float* pmax = w; w += NB * 128;
    short* Bswz1 = (short*)w; w += 192 * 64 / 2;
    short* Bswz2 = (short*)w; w += 320 * 128 / 2;
    int* deg    = (int*)w; w += NN;
    int* cursor = (int*)w; w += NN;
    int* excl   = (int*)w; w += NN;
    int* part   = (int*)w; w += 128;
    int* rowptr = (int*)w; w += NN + 8;
    int* colidx = (int*)w; w += ETOT;

    // init + weight prep
    hipLaunchKernelGGL(k_init, dim3(256), dim3(256), 0, stream, deg, cursor, sums, cnt, pmax);
    hipLaunchKernelGGL(k_prep_w, dim3(160), dim3(256), 0, stream, K1, K2, Bswz1, Bswz2);

    // CSR build (shared by both GAT layers)
    hipLaunchKernelGGL(k_count, dim3(ETOT / 256), dim3(256), 0, stream, ei, deg);
    hipLaunchKernelGGL(k_scan1, dim3(NN / 256), dim3(256), 0, stream, deg, excl, part);
    hipLaunchKernelGGL(k_scan2, dim3(1), dim3(128), 0, stream, part);
    hipLaunchKernelGGL(k_scan3, dim3(NN / 256), dim3(256), 0, stream, excl, part, rowptr);
    hipLaunchKernelGGL(k_scatter, dim3(ETOT / 256), dim3(256), 0, stream, ei, rowptr, cursor, colidx);

    // protein branch (MFMA)
    hipLaunchKernelGGL(k_protein, dim3(NB * 8), dim3(256), 0, stream,
                       seq, Pe, Bswz1, bk1, Bswz2, bk2, pmax);
    hipLaunchKernelGGL(k_prot_fc, dim3(NB), dim3(256), 0, stream, pmax, Wp, bp, prot);

    // GAT layer 1
    hipLaunchKernelGGL(k_gat1_hatt, dim3(NN), dim3(128), 0, stream,
                       x, W1, a_s1, a_d1, h1, as1, ad1);
    hipLaunchKernelGGL(k_agg<2>, dim3(NN / 2), dim3(256), 0, stream,
                       rowptr, colidx, h1, as1, ad1, b1, g1);

    // GAT layer 2
    hipLaunchKernelGGL(k_gat2_hatt, dim3(NN), dim3(128), 0, stream,
                       g1, W2, a_s2, a_d2, h2, as2, ad2);
    hipLaunchKernelGGL(k_agg<1>, dim3(NN / 2), dim3(256), 0, stream,
                       rowptr, colidx, h2, as2, ad2, b2, g2);

    // pool + drug FC
    hipLaunchKernelGGL(k_pool, dim3(NN / 96), dim3(128), 0, stream, g2, batch, sums, cnt);
    hipLaunchKernelGGL(k_drug_fc, dim3(NG), dim3(256), 0, stream, sums, cnt, Wd, bd, drug);

    // head
    hipLaunchKernelGGL(k_head, dim3(NG), dim3(128), 0, stream,
                       drug, prot, Wf1, bf1, Wf2, bf2, Wo, bo, out);
}

// Round 5
// 426.902 us; speedup vs baseline: 5.6014x; 1.1142x over previous
//
#include <hip/hip_runtime.h>
#include <hip/hip_bf16.h>
#include <math.h>

#define NN 24576
#define NE 98304
#define ETOT (NE + NN)
#define NG 512
#define NB 512
#define LL 1000
#define TL 128

typedef __attribute__((ext_vector_type(8))) short short8;
typedef __attribute__((ext_vector_type(4))) short short4v;
typedef __attribute__((ext_vector_type(4))) float f32x4;

__device__ inline short f2bf(float x) {
    union { __hip_bfloat16 b; short s; } u;
    u.b = __float2bfloat16(x);
    return u.s;
}

__device__ inline float bf2f(short s) {
    return __uint_as_float(((unsigned)(unsigned short)s) << 16);
}

__device__ inline void atomicMaxFloat(float* addr, float val) {
    int* ai = (int*)addr;
    int old = __float_as_int(*addr);
    while (__int_as_float(old) < val) {
        int assumed = old;
        old = atomicCAS(ai, assumed, __float_as_int(val));
        if (old == assumed) break;
    }
}

// ---------------- init ----------------
__global__ void k_init(int* deg, int* cursor, float* sums, float* cnt, float* pmax) {
    int i = blockIdx.x * 256 + threadIdx.x;   // 65536 threads
    if (i < NN) { deg[i] = 0; cursor[i] = 0; }
    if (i < NG * 128) sums[i] = 0.f;
    if (i < NG) cnt[i] = 0.f;
    if (i < NB * 128) pmax[i] = -1e30f;
}

// ---------------- CSR build ----------------
__global__ void k_count(const int* ei, int* deg) {
    int e = blockIdx.x * 256 + threadIdx.x;
    if (e >= ETOT) return;
    int d = (e < NE) ? ei[NE + e] : e - NE;
    atomicAdd(&deg[d], 1);
}

__global__ void k_scan1(const int* deg, int* excl, int* part) {
    __shared__ int s[256];
    int b = blockIdx.x, t = threadIdx.x, i = b * 256 + t;
    int v = deg[i];
    s[t] = v;
    __syncthreads();
    for (int o = 1; o < 256; o <<= 1) {
        int x = (t >= o) ? s[t - o] : 0;
        __syncthreads();
        s[t] += x;
        __syncthreads();
    }
    excl[i] = s[t] - v;
    if (t == 255) part[b] = s[t];
}

__global__ void k_scan2(int* part) {   // 96 partials, 1 block
    __shared__ int s[96];
    int t = threadIdx.x;
    if (t < 96) s[t] = part[t];
    __syncthreads();
    if (t == 0) {
        int run = 0;
        for (int i = 0; i < 96; i++) { int v = s[i]; s[i] = run; run += v; }
    }
    __syncthreads();
    if (t < 96) part[t] = s[t];
}

__global__ void k_scan3(const int* excl, const int* part, int* rowptr) {
    int i = blockIdx.x * 256 + threadIdx.x;
    rowptr[i] = excl[i] + part[i >> 8];
    if (i == 0) rowptr[NN] = ETOT;
}

__global__ void k_scatter(const int* ei, const int* rowptr, int* cursor, int* colidx) {
    int e = blockIdx.x * 256 + threadIdx.x;
    if (e >= ETOT) return;
    int s, d;
    if (e < NE) { s = ei[e]; d = ei[NE + e]; }
    else { s = d = e - NE; }
    int pos = atomicAdd(&cursor[d], 1);
    colidx[rowptr[d] + pos] = s;
}

// ---------------- GAT layer 1: h = x@W1 (K=5), fused att dots; grid-stride ----------------
__global__ void k_gat1_hatt(const float* x, const float* W1, const float* asrc, const float* adst,
                            float* h1, float* as_, float* ad_) {
    int idx = blockIdx.x * 256 + threadIdx.x;   // NN*128
    int n = idx >> 7, j = idx & 127;
    float acc = 0.f;
#pragma unroll
    for (int f = 0; f < 5; f++) acc += x[n * 5 + f] * W1[f * 128 + j];
    h1[idx] = acc;
    int hd = j >> 6, c = j & 63;                // hd is wave-uniform
    float ps = acc * asrc[hd * 64 + c];
    float pd = acc * adst[hd * 64 + c];
    for (int off = 32; off > 0; off >>= 1) {
        ps += __shfl_down(ps, off, 64);
        pd += __shfl_down(pd, off, 64);
    }
    if (c == 0) { as_[n * 2 + hd] = ps; ad_[n * 2 + hd] = pd; }
}

// ---------------- GAT layer 2 matmul via 3-term split-bf16 MFMA ----------------
// h2 = g1 @ W2, M=24576, K=128, N=128; block = 64 rows. a = ah+al, b = bh+bl;
// a*b ~= ah*bh + ah*bl + al*bh (error ~2^-17 rel). Epilogue fuses as2/ad2 dots.
#define ASTR 136
__global__ __launch_bounds__(256, 2) void k_gat2_mm(
    const float* g1, const short* Bh, const short* Bl,
    const float* asrc, const float* adst, float* h2, float* as_, float* ad_) {
    __shared__ __align__(16) short Ah[64 * ASTR];   // 17.4 KB
    __shared__ __align__(16) short Al[64 * ASTR];   // 17.4 KB
    int t = threadIdx.x;
    int m0 = blockIdx.x * 64;
    int wv = t >> 6, lane = t & 63;
    int ln15 = lane & 15, quad = lane >> 4;

    // stage A block: 64 rows x 128 k fp32 -> hi/lo bf16
    for (int i = t; i < 64 * 32; i += 256) {
        int row = i >> 5, c4 = (i & 31) * 4;
        float4 v = *(const float4*)&g1[(m0 + row) * 128 + c4];
        short4v hi, lo;
        hi.x = f2bf(v.x); lo.x = f2bf(v.x - bf2f(hi.x));
        hi.y = f2bf(v.y); lo.y = f2bf(v.y - bf2f(hi.y));
        hi.z = f2bf(v.z); lo.z = f2bf(v.z - bf2f(hi.z));
        hi.w = f2bf(v.w); lo.w = f2bf(v.w - bf2f(hi.w));
        *(short4v*)&Ah[row * ASTR + c4] = hi;
        *(short4v*)&Al[row * ASTR + c4] = lo;
    }
    __syncthreads();

    // wave wv owns M-tile wv (16 rows); 8 N-tiles; K = 4 kb steps
    f32x4 acc[8];
#pragma unroll
    for (int nt = 0; nt < 8; nt++) acc[nt] = (f32x4){0.f, 0.f, 0.f, 0.f};
    int arow = wv * 16 + ln15;
#pragma unroll
    for (int kb = 0; kb < 4; kb++) {
        int koff = kb * 32 + quad * 8;
        short8 a_hi = *(const short8*)&Ah[arow * ASTR + koff];
        short8 a_lo = *(const short8*)&Al[arow * ASTR + koff];
#pragma unroll
        for (int nt = 0; nt < 8; nt++) {
            short8 bh = *(const short8*)&Bh[((kb * 8 + nt) * 64 + lane) * 8];
            short8 bl = *(const short8*)&Bl[((kb * 8 + nt) * 64 + lane) * 8];
            acc[nt] = __builtin_amdgcn_mfma_f32_16x16x32_bf16(a_hi, bh, acc[nt], 0, 0, 0);
            acc[nt] = __builtin_amdgcn_mfma_f32_16x16x32_bf16(a_hi, bl, acc[nt], 0, 0, 0);
            acc[nt] = __builtin_amdgcn_mfma_f32_16x16x32_bf16(a_lo, bh, acc[nt], 0, 0, 0);
        }
    }

    // epilogue: store h2, fused attention dots (reduce over cols)
    float ps[4] = {0.f, 0.f, 0.f, 0.f}, pd[4] = {0.f, 0.f, 0.f, 0.f};
#pragma unroll
    for (int nt = 0; nt < 8; nt++) {
        int col = nt * 16 + ln15;
        float asv = asrc[col], adv = adst[col];
#pragma unroll
        for (int r = 0; r < 4; r++) {
            float v = acc[nt][r];
            int n = m0 + wv * 16 + quad * 4 + r;
            h2[n * 128 + col] = v;
            ps[r] += v * asv;
            pd[r] += v * adv;
        }
    }
#pragma unroll
    for (int r = 0; r < 4; r++) {
#pragma unroll
        for (int mask = 1; mask < 16; mask <<= 1) {
            ps[r] += __shfl_xor(ps[r], mask, 64);
            pd[r] += __shfl_xor(pd[r], mask, 64);
        }
    }
    if (ln15 == 0) {
#pragma unroll
        for (int r = 0; r < 4; r++) {
            int n = m0 + wv * 16 + quad * 4 + r;
            as_[n] = ps[r];
            ad_[n] = pd[r];
        }
    }
}

// ---------------- dst-centric GAT aggregation: online softmax, chunked prefetch ----------------
template <int H>
__global__ void k_agg(const int* rowptr, const int* colidx, const float* h,
                      const float* as_, const float* ad_, const float* bias, float* g) {
    int t = threadIdx.x;
    int d = blockIdx.x * 2 + (t >> 7);   // 2 nodes / 256-thr block
    int j = t & 127;
    int hd = (H == 2) ? (j >> 6) : 0;
    float adv = ad_[d * H + hd];
    int p0 = rowptr[d], p1 = rowptr[d + 1];
    float m = -1e30f, den = 0.f, acc = 0.f;
    for (int pc = p0; pc < p1; pc += 4) {
        int sarr[4]; float ev[4], hv[4];
#pragma unroll
        for (int i = 0; i < 4; i++) {
            int pp = pc + i;
            sarr[i] = colidx[pp < p1 ? pp : p1 - 1];
        }
#pragma unroll
        for (int i = 0; i < 4; i++) {
            ev[i] = as_[sarr[i] * H + hd];
            hv[i] = h[sarr[i] * 128 + j];
        }
#pragma unroll
        for (int i = 0; i < 4; i++) {
            if (pc + i < p1) {
                float e = ev[i] + adv;
                e = e >= 0.f ? e : 0.2f * e;
                float nm = fmaxf(m, e);
                float sc = __expf(m - nm);
                float w = __expf(e - nm);
                den = den * sc + w;
                acc = acc * sc + w * hv[i];
                m = nm;
            }
        }
    }
    float v = acc / (den + 1e-16f) + bias[j];
    g[d * 128 + j] = v > 0.f ? v : __expf(v) - 1.f;
}

// ---------------- mean pool (sorted batch -> run-length local accumulate) ----------------
__global__ void k_pool(const float* g2, const int* batch, float* sums, float* cnt) {
    __shared__ int sb[96];
    int blk = blockIdx.x, j = threadIdx.x;
    int n0 = blk * 96;
    if (j < 96) sb[j] = batch[n0 + j];
    __syncthreads();
    int cur = sb[0], runStart = 0;
    float acc = 0.f;
    for (int q = 0; q < 96; q++) {
        int bb = sb[q];
        if (bb != cur) {
            atomicAdd(&sums[cur * 128 + j], acc);
            if (j == 0) atomicAdd(&cnt[cur], (float)(q - runStart));
            cur = bb; acc = 0.f; runStart = q;
        }
        acc += g2[(n0 + q) * 128 + j];
    }
    atomicAdd(&sums[cur * 128 + j], acc);
    if (j == 0) atomicAdd(&cnt[cur], (float)(96 - runStart));
}

// ---------------- drug FC ----------------
__global__ void k_drug_fc(const float* sums, const float* cnt, const float* Wd, const float* bd,
                          float* drug) {
    int idx = blockIdx.x * 256 + threadIdx.x;   // NG*256
    if (idx >= NG * 256) return;
    int g = idx >> 8, o = idx & 255;
    float c = cnt[g]; c = c < 1.f ? 1.f : c;
    float inv = 1.f / c;
    float acc = bd[o];
#pragma unroll 8
    for (int i = 0; i < 128; i++) acc += sums[g * 128 + i] * inv * Wd[i * 256 + o];
    drug[idx] = acc > 0.f ? acc : 0.f;
}

// ---------------- weight swizzle to MFMA B-fragment order (bf16) ----------------
__global__ void k_prep_w(const float* K1, const float* K2, const float* W2,
                         short* Bswz1, short* Bswz2, short* Bh2, short* Bl2) {
    int idx = blockIdx.x * 256 + threadIdx.x;
    if (idx < 192 * 64) {       // B1: K=192 (6 kb), N=64 (4 nt)
        int j = idx & 7, lane = (idx >> 3) & 63, rest = idx >> 9;
        int nt = rest & 3, kb = rest >> 2;
        int k = kb * 32 + ((lane >> 4) << 3) + j;
        int n = nt * 16 + (lane & 15);
        int kk = k >> 6, i = k & 63;            // B1[k][n] = K1[n][i][kk]
        Bswz1[idx] = f2bf(K1[n * 192 + i * 3 + kk]);
    }
    if (idx < 320 * 128) {      // B2: K=320 (10 kb), N=128 (8 nt)
        int j = idx & 7, lane = (idx >> 3) & 63, rest = idx >> 9;
        int nt = rest & 7, kb = rest >> 3;
        int k = kb * 32 + ((lane >> 4) << 3) + j;
        int n = nt * 16 + (lane & 15);
        int kk = k / 64, i = k % 64;            // B2[k][n] = K2[n][i][kk]
        Bswz2[idx] = f2bf(K2[n * 320 + i * 5 + kk]);
    }
    if (idx < 128 * 128) {      // W2 hi/lo: K=128 (4 kb), N=128 (8 nt)
        int j = idx & 7, lane = (idx >> 3) & 63, rest = idx >> 9;
        int nt = rest & 7, kb = rest >> 3;
        int k = kb * 32 + ((lane >> 4) << 3) + j;
        int n = nt * 16 + (lane & 15);
        float v = W2[k * 128 + n];
        short hh = f2bf(v);
        Bh2[idx] = hh;
        Bl2[idx] = f2bf(v - bf2f(hh));
    }
}

// ---------------- fused protein via MFMA bf16, TL=128 (unchanged from R4) ----------------
#define SSTR 72
__global__ __launch_bounds__(256, 4) void k_protein(
    const int* seq, const float* Pe, const short* Bswz1, const float* bk1,
    const short* Bswz2, const float* bk2, float* pmax) {
    __shared__ __align__(16) short sEmb[134 * SSTR];
    __shared__ __align__(16) short s1[132 * SSTR];

    int b = blockIdx.x >> 3;
    int tile = blockIdx.x & 7;
    int t0 = tile * TL;
    int t = threadIdx.x;
    int wv = t >> 6, lane = t & 63;
    int ln15 = lane & 15, quad = lane >> 4;

    for (int j0 = 0; j0 < 134; j0 += 64) {
        int j = j0 + (t >> 2);
        if (j < 134) {
            int c0 = (t & 3) * 16;
            int l = t0 - 3 + j;
            int id = (l >= 0 && l < LL) ? seq[b * LL + l] : -1;
            short* dst = &sEmb[j * SSTR + c0];
            if (id >= 0) {
                const float4* src = (const float4*)&Pe[id * 64 + c0];
#pragma unroll
                for (int v = 0; v < 4; v++) {
                    float4 f = src[v];
                    short4v o;
                    o.x = f2bf(f.x); o.y = f2bf(f.y); o.z = f2bf(f.z); o.w = f2bf(f.w);
                    *(short4v*)(dst + v * 4) = o;
                }
            } else {
#pragma unroll
                for (int v = 0; v < 4; v++) *(short4v*)(dst + v * 4) = (short4v){0, 0, 0, 0};
            }
        }
    }
    __syncthreads();

    {
        short8 b1f[6];
#pragma unroll
        for (int kb = 0; kb < 6; kb++)
            b1f[kb] = *(const short8*)&Bswz1[((kb * 4 + wv) * 64 + lane) * 8];
        int col = wv * 16 + ln15;
        float bias = bk1[col];
        const int M0[9] = {0, 16, 32, 48, 64, 80, 96, 112, 116};
#pragma unroll
        for (int mi = 0; mi < 9; mi++) {
            int arow = M0[mi] + ln15;
            f32x4 acc = {0.f, 0.f, 0.f, 0.f};
#pragma unroll
            for (int kb = 0; kb < 6; kb++) {
                int koff = kb * 32 + quad * 8;
                int kk = koff >> 6, i0 = koff & 63;
                short8 a = *(const short8*)&sEmb[(arow + kk) * SSTR + i0];
                acc = __builtin_amdgcn_mfma_f32_16x16x32_bf16(a, b1f[kb], acc, 0, 0, 0);
            }
#pragma unroll
            for (int r = 0; r < 4; r++) {
                int q = M0[mi] + quad * 4 + r;
                if (q < 132) {
                    int l = t0 - 2 + q;
                    float v = acc[r] + bias;
                    v = v > 0.f ? v : __expf(v) - 1.f;
                    s1[q * SSTR + col] = (l >= 0 && l < LL) ? f2bf(v) : (short)0;
                }
            }
        }
    }
    __syncthreads();

    f32x4 acc2[2][8];
#pragma unroll
    for (int i = 0; i < 2; i++)
#pragma unroll
        for (int nt = 0; nt < 8; nt++) acc2[i][nt] = (f32x4){0.f, 0.f, 0.f, 0.f};
    int ar0 = (2 * wv) * 16 + ln15;
    int ar1 = (2 * wv + 1) * 16 + ln15;
#pragma unroll 2
    for (int kb = 0; kb < 10; kb++) {
        int koff = kb * 32 + quad * 8;
        int kk = koff >> 6, i0 = koff & 63;
        short8 a0 = *(const short8*)&s1[(ar0 + kk) * SSTR + i0];
        short8 a1 = *(const short8*)&s1[(ar1 + kk) * SSTR + i0];
#pragma unroll
        for (int nt = 0; nt < 8; nt++) {
            short8 bb = *(const short8*)&Bswz2[((kb * 8 + nt) * 64 + lane) * 8];
            acc2[0][nt] = __builtin_amdgcn_mfma_f32_16x16x32_bf16(a0, bb, acc2[0][nt], 0, 0, 0);
            acc2[1][nt] = __builtin_amdgcn_mfma_f32_16x16x32_bf16(a1, bb, acc2[1][nt], 0, 0, 0);
        }
    }
#pragma unroll
    for (int nt = 0; nt < 8; nt++) {
        int col = nt * 16 + ln15;
        float bias = bk2[col];
        float mx = -1e30f;
#pragma unroll
        for (int i = 0; i < 2; i++) {
#pragma unroll
            for (int r = 0; r < 4; r++) {
                int p = (2 * wv + i) * 16 + quad * 4 + r;
                int l = t0 + p;
                float v = acc2[i][nt][r] + bias;
                v = v > 0.f ? v : __expf(v) - 1.f;
                if (l < LL) mx = fmaxf(mx, v);
            }
        }
        mx = fmaxf(mx, __shfl_xor(mx, 16, 64));
        mx = fmaxf(mx, __shfl_xor(mx, 32, 64));
        if (quad == 0) atomicMaxFloat(&pmax[b * 128 + col], mx);
    }
}

// ---------------- protein FC ----------------
__global__ void k_prot_fc(const float* pmax, const float* Wp, const float* bp, float* prot) {
    int idx = blockIdx.x * 256 + threadIdx.x;   // NB*256
    if (idx >= NB * 256) return;
    int g = idx >> 8, o = idx & 255;
    float acc = bp[o];
#pragma unroll 8
    for (int i = 0; i < 128; i++) acc += pmax[g * 128 + i] * Wp[i * 256 + o];
    prot[idx] = acc > 0.f ? acc : 0.f;
}

// ---------------- head MLP ----------------
__global__ void k_head(const float* drug, const float* prot, const float* Wf1, const float* bf1,
                       const float* Wf2, const float* bf2, const float* Wo, const float* bo,
                       float* out) {
    __shared__ float in[512];
    __shared__ float hh[128];
    __shared__ float h2s[64];
    int g = blockIdx.x, t = threadIdx.x;   // 128 threads
    in[t] = drug[g * 256 + t];
    in[128 + t] = drug[g * 256 + 128 + t];
    in[256 + t] = prot[g * 256 + t];
    in[384 + t] = prot[g * 256 + 128 + t];
    __syncthreads();
    float acc = bf1[t];
#pragma unroll 8
    for (int c = 0; c < 512; c++) acc += in[c] * Wf1[c * 128 + t];
    hh[t] = acc > 0.f ? acc : 0.f;
    __syncthreads();
    if (t < 64) {
        float a2 = bf2[t];
#pragma unroll 8
        for (int c = 0; c < 128; c++) a2 += hh[c] * Wf2[c * 64 + t];
        h2s[t] = a2 > 0.f ? a2 : 0.f;
    }
    __syncthreads();
    if (t == 0) {
        float o = bo[0];
#pragma unroll 8
        for (int c = 0; c < 64; c++) o += h2s[c] * Wo[c];
        out[g] = o;
    }
}

extern "C" void kernel_launch(void* const* d_in, const int* in_sizes, int n_in,
                              void* d_out, int out_size, void* d_ws, size_t ws_size,
                              hipStream_t stream) {
    (void)in_sizes; (void)n_in; (void)out_size; (void)ws_size;
    const float* x   = (const float*)d_in[0];
    const int* ei    = (const int*)d_in[1];
    const int* batch = (const int*)d_in[2];
    const int* seq   = (const int*)d_in[3];
    const float* W1  = (const float*)d_in[4];
    const float* a_s1 = (const float*)d_in[5];
    const float* a_d1 = (const float*)d_in[6];
    const float* b1  = (const float*)d_in[7];
    const float* W2  = (const float*)d_in[8];
    const float* a_s2 = (const float*)d_in[9];
    const float* a_d2 = (const float*)d_in[10];
    const float* b2  = (const float*)d_in[11];
    const float* Wd  = (const float*)d_in[12];
    const float* bd  = (const float*)d_in[13];
    const float* Pe  = (const float*)d_in[14];
    const float* K1  = (const float*)d_in[15];
    const float* bk1 = (const float*)d_in[16];
    const float* K2  = (const float*)d_in[17];
    const float* bk2 = (const float*)d_in[18];
    const float* Wp  = (const float*)d_in[19];
    const float* bp  = (const float*)d_in[20];
    const float* Wf1 = (const float*)d_in[21];
    const float* bf1 = (const float*)d_in[22];
    const float* Wf2 = (const float*)d_in[23];
    const float* bf2 = (const float*)d_in[24];
    const float* Wo  = (const float*)d_in[25];
    const float* bo  = (const float*)d_in[26];
    float* out = (float*)d_out;

    float* w = (float*)d_ws;
    float* h1   = w; w += NN * 128;
    float* g1   = w; w += NN * 128;
    float* h2   = w; w += NN * 128;
    float* g2   = w; w += NN * 128;
    float* as1  = w; w += NN * 2;
    float* ad1  = w; w += NN * 2;
    float* as2  = w; w += NN;
    float* ad2  = w; w += NN;
    float* sums = w; w += NG * 128;
    float* cnt  = w; w += NG;
    float* drug = w; w += NG * 256;
    float* prot = w; w += NB * 256;
    float* pmax = w; w += NB * 128;
    short* Bswz1 = (short*)w; w += 192 * 64 / 2;
    short* Bswz2 = (short*)w; w += 320 * 128 / 2;
    short* Bh2  = (short*)w; w += 128 * 128 / 2;
    short* Bl2  = (short*)w; w += 128 * 128 / 2;
    int* deg    = (int*)w; w += NN;
    int* cursor = (int*)w; w += NN;
    int* excl   = (int*)w; w += NN;
    int* part   = (int*)w; w += 128;
    int* rowptr = (int*)w; w += NN + 8;
    int* colidx = (int*)w; w += ETOT;

    // init + weight prep
    hipLaunchKernelGGL(k_init, dim3(256), dim3(256), 0, stream, deg, cursor, sums, cnt, pmax);
    hipLaunchKernelGGL(k_prep_w, dim3(160), dim3(256), 0, stream,
                       K1, K2, W2, Bswz1, Bswz2, Bh2, Bl2);

    // CSR build
    hipLaunchKernelGGL(k_count, dim3(ETOT / 256), dim3(256), 0, stream, ei, deg);
    hipLaunchKernelGGL(k_scan1, dim3(NN / 256), dim3(256), 0, stream, deg, excl, part);
    hipLaunchKernelGGL(k_scan2, dim3(1), dim3(128), 0, stream, part);
    hipLaunchKernelGGL(k_scan3, dim3(NN / 256), dim3(256), 0, stream, excl, part, rowptr);
    hipLaunchKernelGGL(k_scatter, dim3(ETOT / 256), dim3(256), 0, stream, ei, rowptr, cursor, colidx);

    // protein branch (MFMA)
    hipLaunchKernelGGL(k_protein, dim3(NB * 8), dim3(256), 0, stream,
                       seq, Pe, Bswz1, bk1, Bswz2, bk2, pmax);
    hipLaunchKernelGGL(k_prot_fc, dim3(NB), dim3(256), 0, stream, pmax, Wp, bp, prot);

    // GAT layer 1
    hipLaunchKernelGGL(k_gat1_hatt, dim3(NN * 128 / 256), dim3(256), 0, stream,
                       x, W1, a_s1, a_d1, h1, as1, ad1);
    hipLaunchKernelGGL(k_agg<2>, dim3(NN / 2), dim3(256), 0, stream,
                       rowptr, colidx, h1, as1, ad1, b1, g1);

    // GAT layer 2 (MFMA split-bf16 matmul + fused att dots)
    hipLaunchKernelGGL(k_gat2_mm, dim3(NN / 64), dim3(256), 0, stream,
                       g1, Bh2, Bl2, a_s2, a_d2, h2, as2, ad2);
    hipLaunchKernelGGL(k_agg<1>, dim3(NN / 2), dim3(256), 0, stream,
                       rowptr, colidx, h2, as2, ad2, b2, g2);

    // pool + drug FC
    hipLaunchKernelGGL(k_pool, dim3(NN / 96), dim3(128), 0, stream, g2, batch, sums, cnt);
    hipLaunchKernelGGL(k_drug_fc, dim3(NG), dim3(256), 0, stream, sums, cnt, Wd, bd, drug);

    // head
    hipLaunchKernelGGL(k_head, dim3(NG), dim3(128), 0, stream,
                       drug, prot, Wf1, bf1, Wf2, bf2, Wo, bo, out);
}

// Round 6
// 386.178 us; speedup vs baseline: 6.1921x; 1.1055x over previous
//
#include <hip/hip_runtime.h>
#include <hip/hip_bf16.h>
#include <math.h>

#define NN 24576
#define NE 98304
#define ETOT (NE + NN)
#define NG 512
#define NB 512
#define LL 1000
#define TL 124
#define NTILE 9

typedef __attribute__((ext_vector_type(8))) short short8;
typedef __attribute__((ext_vector_type(4))) short short4v;
typedef __attribute__((ext_vector_type(4))) float f32x4;

__device__ inline short f2bf(float x) {
    union { __hip_bfloat16 b; short s; } u;
    u.b = __float2bfloat16(x);
    return u.s;
}

__device__ inline float bf2f(short s) {
    return __uint_as_float(((unsigned)(unsigned short)s) << 16);
}

__device__ inline void atomicMaxFloat(float* addr, float val) {
    int* ai = (int*)addr;
    int old = __float_as_int(*addr);
    while (__int_as_float(old) < val) {
        int assumed = old;
        old = atomicCAS(ai, assumed, __float_as_int(val));
        if (old == assumed) break;
    }
}

// ---------------- init ----------------
__global__ void k_init(int* deg, int* cursor, float* sums, float* cnt, float* pmax) {
    int i = blockIdx.x * 256 + threadIdx.x;   // 65536 threads
    if (i < NN) { deg[i] = 0; cursor[i] = 0; }
    if (i < NG * 128) sums[i] = 0.f;
    if (i < NG) cnt[i] = 0.f;
    if (i < NB * 128) pmax[i] = -1e30f;
}

// ---------------- CSR build ----------------
__global__ void k_count(const int* ei, int* deg) {
    int e = blockIdx.x * 256 + threadIdx.x;
    if (e >= ETOT) return;
    int d = (e < NE) ? ei[NE + e] : e - NE;
    atomicAdd(&deg[d], 1);
}

__global__ void k_scan1(const int* deg, int* excl, int* part) {
    __shared__ int s[256];
    int b = blockIdx.x, t = threadIdx.x, i = b * 256 + t;
    int v = deg[i];
    s[t] = v;
    __syncthreads();
    for (int o = 1; o < 256; o <<= 1) {
        int x = (t >= o) ? s[t - o] : 0;
        __syncthreads();
        s[t] += x;
        __syncthreads();
    }
    excl[i] = s[t] - v;
    if (t == 255) part[b] = s[t];
}

__global__ void k_scan2(int* part) {   // 96 partials, 1 block
    __shared__ int s[96];
    int t = threadIdx.x;
    if (t < 96) s[t] = part[t];
    __syncthreads();
    if (t == 0) {
        int run = 0;
        for (int i = 0; i < 96; i++) { int v = s[i]; s[i] = run; run += v; }
    }
    __syncthreads();
    if (t < 96) part[t] = s[t];
}

__global__ void k_scan3(const int* excl, const int* part, int* rowptr) {
    int i = blockIdx.x * 256 + threadIdx.x;
    rowptr[i] = excl[i] + part[i >> 8];
    if (i == 0) rowptr[NN] = ETOT;
}

__global__ void k_scatter(const int* ei, const int* rowptr, int* cursor, int* colidx) {
    int e = blockIdx.x * 256 + threadIdx.x;
    if (e >= ETOT) return;
    int s, d;
    if (e < NE) { s = ei[e]; d = ei[NE + e]; }
    else { s = d = e - NE; }
    int pos = atomicAdd(&cursor[d], 1);
    colidx[rowptr[d] + pos] = s;
}

// ---------------- GAT layer 1: h = x@W1 (K=5), fused att dots; grid-stride ----------------
__global__ void k_gat1_hatt(const float* x, const float* W1, const float* asrc, const float* adst,
                            float* h1, float* as_, float* ad_) {
    int idx = blockIdx.x * 256 + threadIdx.x;   // NN*128
    int n = idx >> 7, j = idx & 127;
    float acc = 0.f;
#pragma unroll
    for (int f = 0; f < 5; f++) acc += x[n * 5 + f] * W1[f * 128 + j];
    h1[idx] = acc;
    int hd = j >> 6, c = j & 63;                // hd is wave-uniform
    float ps = acc * asrc[hd * 64 + c];
    float pd = acc * adst[hd * 64 + c];
    for (int off = 32; off > 0; off >>= 1) {
        ps += __shfl_down(ps, off, 64);
        pd += __shfl_down(pd, off, 64);
    }
    if (c == 0) { as_[n * 2 + hd] = ps; ad_[n * 2 + hd] = pd; }
}

// ---------------- GAT layer 2 matmul via 3-term split-bf16 MFMA ----------------
#define ASTR 136
__global__ __launch_bounds__(256, 2) void k_gat2_mm(
    const float* g1, const short* Bh, const short* Bl,
    const float* asrc, const float* adst, float* h2, float* as_, float* ad_) {
    __shared__ __align__(16) short Ah[64 * ASTR];
    __shared__ __align__(16) short Al[64 * ASTR];
    int t = threadIdx.x;
    int m0 = blockIdx.x * 64;
    int wv = t >> 6, lane = t & 63;
    int ln15 = lane & 15, quad = lane >> 4;

    for (int i = t; i < 64 * 32; i += 256) {
        int row = i >> 5, c4 = (i & 31) * 4;
        float4 v = *(const float4*)&g1[(m0 + row) * 128 + c4];
        short4v hi, lo;
        hi.x = f2bf(v.x); lo.x = f2bf(v.x - bf2f(hi.x));
        hi.y = f2bf(v.y); lo.y = f2bf(v.y - bf2f(hi.y));
        hi.z = f2bf(v.z); lo.z = f2bf(v.z - bf2f(hi.z));
        hi.w = f2bf(v.w); lo.w = f2bf(v.w - bf2f(hi.w));
        *(short4v*)&Ah[row * ASTR + c4] = hi;
        *(short4v*)&Al[row * ASTR + c4] = lo;
    }
    __syncthreads();

    f32x4 acc[8];
#pragma unroll
    for (int nt = 0; nt < 8; nt++) acc[nt] = (f32x4){0.f, 0.f, 0.f, 0.f};
    int arow = wv * 16 + ln15;
#pragma unroll
    for (int kb = 0; kb < 4; kb++) {
        int koff = kb * 32 + quad * 8;
        short8 a_hi = *(const short8*)&Ah[arow * ASTR + koff];
        short8 a_lo = *(const short8*)&Al[arow * ASTR + koff];
#pragma unroll
        for (int nt = 0; nt < 8; nt++) {
            short8 bh = *(const short8*)&Bh[((kb * 8 + nt) * 64 + lane) * 8];
            short8 bl = *(const short8*)&Bl[((kb * 8 + nt) * 64 + lane) * 8];
            acc[nt] = __builtin_amdgcn_mfma_f32_16x16x32_bf16(a_hi, bh, acc[nt], 0, 0, 0);
            acc[nt] = __builtin_amdgcn_mfma_f32_16x16x32_bf16(a_hi, bl, acc[nt], 0, 0, 0);
            acc[nt] = __builtin_amdgcn_mfma_f32_16x16x32_bf16(a_lo, bh, acc[nt], 0, 0, 0);
        }
    }

    float ps[4] = {0.f, 0.f, 0.f, 0.f}, pd[4] = {0.f, 0.f, 0.f, 0.f};
#pragma unroll
    for (int nt = 0; nt < 8; nt++) {
        int col = nt * 16 + ln15;
        float asv = asrc[col], adv = adst[col];
#pragma unroll
        for (int r = 0; r < 4; r++) {
            float v = acc[nt][r];
            int n = m0 + wv * 16 + quad * 4 + r;
            h2[n * 128 + col] = v;
            ps[r] += v * asv;
            pd[r] += v * adv;
        }
    }
#pragma unroll
    for (int r = 0; r < 4; r++) {
#pragma unroll
        for (int mask = 1; mask < 16; mask <<= 1) {
            ps[r] += __shfl_xor(ps[r], mask, 64);
            pd[r] += __shfl_xor(pd[r], mask, 64);
        }
    }
    if (ln15 == 0) {
#pragma unroll
        for (int r = 0; r < 4; r++) {
            int n = m0 + wv * 16 + quad * 4 + r;
            as_[n] = ps[r];
            ad_[n] = pd[r];
        }
    }
}

// ---------------- dst-centric GAT aggregation: online softmax, chunked prefetch ----------------
template <int H>
__global__ void k_agg(const int* rowptr, const int* colidx, const float* h,
                      const float* as_, const float* ad_, const float* bias, float* g) {
    int t = threadIdx.x;
    int d = blockIdx.x * 2 + (t >> 7);   // 2 nodes / 256-thr block
    int j = t & 127;
    int hd = (H == 2) ? (j >> 6) : 0;
    float adv = ad_[d * H + hd];
    int p0 = rowptr[d], p1 = rowptr[d + 1];
    float m = -1e30f, den = 0.f, acc = 0.f;
    for (int pc = p0; pc < p1; pc += 4) {
        int sarr[4]; float ev[4], hv[4];
#pragma unroll
        for (int i = 0; i < 4; i++) {
            int pp = pc + i;
            sarr[i] = colidx[pp < p1 ? pp : p1 - 1];
        }
#pragma unroll
        for (int i = 0; i < 4; i++) {
            ev[i] = as_[sarr[i] * H + hd];
            hv[i] = h[sarr[i] * 128 + j];
        }
#pragma unroll
        for (int i = 0; i < 4; i++) {
            if (pc + i < p1) {
                float e = ev[i] + adv;
                e = e >= 0.f ? e : 0.2f * e;
                float nm = fmaxf(m, e);
                float sc = __expf(m - nm);
                float w = __expf(e - nm);
                den = den * sc + w;
                acc = acc * sc + w * hv[i];
                m = nm;
            }
        }
    }
    float v = acc / (den + 1e-16f) + bias[j];
    g[d * 128 + j] = v > 0.f ? v : __expf(v) - 1.f;
}

// ---------------- mean pool (sorted batch -> run-length local accumulate) ----------------
__global__ void k_pool(const float* g2, const int* batch, float* sums, float* cnt) {
    __shared__ int sb[96];
    int blk = blockIdx.x, j = threadIdx.x;
    int n0 = blk * 96;
    if (j < 96) sb[j] = batch[n0 + j];
    __syncthreads();
    int cur = sb[0], runStart = 0;
    float acc = 0.f;
    for (int q = 0; q < 96; q++) {
        int bb = sb[q];
        if (bb != cur) {
            atomicAdd(&sums[cur * 128 + j], acc);
            if (j == 0) atomicAdd(&cnt[cur], (float)(q - runStart));
            cur = bb; acc = 0.f; runStart = q;
        }
        acc += g2[(n0 + q) * 128 + j];
    }
    atomicAdd(&sums[cur * 128 + j], acc);
    if (j == 0) atomicAdd(&cnt[cur], (float)(96 - runStart));
}

// ---------------- drug FC ----------------
__global__ void k_drug_fc(const float* sums, const float* cnt, const float* Wd, const float* bd,
                          float* drug) {
    int idx = blockIdx.x * 256 + threadIdx.x;   // NG*256
    if (idx >= NG * 256) return;
    int g = idx >> 8, o = idx & 255;
    float c = cnt[g]; c = c < 1.f ? 1.f : c;
    float inv = 1.f / c;
    float acc = bd[o];
#pragma unroll 8
    for (int i = 0; i < 128; i++) acc += sums[g * 128 + i] * inv * Wd[i * 256 + o];
    drug[idx] = acc > 0.f ? acc : 0.f;
}

// ---------------- weight swizzle to MFMA B-fragment order (bf16) ----------------
__global__ void k_prep_w(const float* K1, const float* K2, const float* W2,
                         short* Bswz1, short* Bswz2, short* Bh2, short* Bl2) {
    int idx = blockIdx.x * 256 + threadIdx.x;
    if (idx < 192 * 64) {       // B1: K=192 (6 kb), N=64 (4 nt)
        int j = idx & 7, lane = (idx >> 3) & 63, rest = idx >> 9;
        int nt = rest & 3, kb = rest >> 2;
        int k = kb * 32 + ((lane >> 4) << 3) + j;
        int n = nt * 16 + (lane & 15);
        int kk = k >> 6, i = k & 63;            // B1[k][n] = K1[n][i][kk]
        Bswz1[idx] = f2bf(K1[n * 192 + i * 3 + kk]);
    }
    if (idx < 320 * 128) {      // B2: K=320 (10 kb), N=128 (8 nt)
        int j = idx & 7, lane = (idx >> 3) & 63, rest = idx >> 9;
        int nt = rest & 7, kb = rest >> 3;
        int k = kb * 32 + ((lane >> 4) << 3) + j;
        int n = nt * 16 + (lane & 15);
        int kk = k / 64, i = k % 64;            // B2[k][n] = K2[n][i][kk]
        Bswz2[idx] = f2bf(K2[n * 320 + i * 5 + kk]);
    }
    if (idx < 128 * 128) {      // W2 hi/lo: K=128 (4 kb), N=128 (8 nt)
        int j = idx & 7, lane = (idx >> 3) & 63, rest = idx >> 9;
        int nt = rest & 7, kb = rest >> 3;
        int k = kb * 32 + ((lane >> 4) << 3) + j;
        int n = nt * 16 + (lane & 15);
        float v = W2[k * 128 + n];
        short hh = f2bf(v);
        Bh2[idx] = hh;
        Bl2[idx] = f2bf(v - bf2f(hh));
    }
}

// ---------------- fused protein via MFMA bf16, TL=124, 64x64-per-wave tiles ----------------
// conv1: M=128 out rows (q = pos t0-2+q), wave = 4 mt x 2 nt (A-reuse x2, B-reuse x4).
// conv2: M=128 (out p = pos t0+p, p<124 valid), N=128, K=320; wave = 4 mt x 4 nt;
//        B-tile (8 KB per kb) staged through LDS (dead sEmb region), double-buffered,
//        register-prefetched so the global load overlaps the 16-MFMA stretch.
#define SSTR 72
__global__ __launch_bounds__(256, 4) void k_protein(
    const int* seq, const float* Pe, const short* Bswz1, const float* bk1,
    const short* Bswz2, const float* bk2, float* pmax) {
    __shared__ __align__(16) short sEmb[130 * SSTR];  // 18.7 KB; B2 dbuf (16 KB) after conv1
    __shared__ __align__(16) short s1[132 * SSTR];    // 19.0 KB

    int b = blockIdx.x / NTILE;
    int tile = blockIdx.x - b * NTILE;
    int t0 = tile * TL;
    int t = threadIdx.x;
    int wv = t >> 6, lane = t & 63;
    int ln15 = lane & 15, quad = lane >> 4;
    int mhalf = wv & 1, nhalf = wv >> 1;

    // ---- phase 0: gather embeddings (fp32 -> bf16); zero OOB rows; zero s1 spill rows ----
    for (int j0 = 0; j0 < 130; j0 += 64) {
        int j = j0 + (t >> 2);
        if (j < 130) {
            int c0 = (t & 3) * 16;
            int l = t0 - 3 + j;
            int id = (l >= 0 && l < LL) ? seq[b * LL + l] : -1;
            short* dst = &sEmb[j * SSTR + c0];
            if (id >= 0) {
                const float4* src = (const float4*)&Pe[id * 64 + c0];
#pragma unroll
                for (int v = 0; v < 4; v++) {
                    float4 f = src[v];
                    short4v o;
                    o.x = f2bf(f.x); o.y = f2bf(f.y); o.z = f2bf(f.z); o.w = f2bf(f.w);
                    *(short4v*)(dst + v * 4) = o;
                }
            } else {
#pragma unroll
                for (int v = 0; v < 4; v++) *(short4v*)(dst + v * 4) = (short4v){0, 0, 0, 0};
            }
        }
    }
    s1[(128 + (t >> 6)) * SSTR + (t & 63)] = 0;   // rows 128..131: im2col spill of mt=7
    __syncthreads();

    // ---- phase 1: conv1. wave = 4 mt x 2 nt; per kb: 2 B + 4 A reads for 8 MFMA ----
    {
        f32x4 acc[4][2];
#pragma unroll
        for (int mi = 0; mi < 4; mi++)
#pragma unroll
            for (int ni = 0; ni < 2; ni++) acc[mi][ni] = (f32x4){0.f, 0.f, 0.f, 0.f};
#pragma unroll
        for (int kb = 0; kb < 6; kb++) {
            int koff = kb * 32 + quad * 8;
            int kk = koff >> 6, i0 = koff & 63;
            short8 b0 = *(const short8*)&Bswz1[((kb * 4 + nhalf * 2 + 0) * 64 + lane) * 8];
            short8 b1 = *(const short8*)&Bswz1[((kb * 4 + nhalf * 2 + 1) * 64 + lane) * 8];
#pragma unroll
            for (int mi = 0; mi < 4; mi++) {
                int arow = (mhalf * 4 + mi) * 16 + ln15 + kk;
                short8 a = *(const short8*)&sEmb[arow * SSTR + i0];
                acc[mi][0] = __builtin_amdgcn_mfma_f32_16x16x32_bf16(a, b0, acc[mi][0], 0, 0, 0);
                acc[mi][1] = __builtin_amdgcn_mfma_f32_16x16x32_bf16(a, b1, acc[mi][1], 0, 0, 0);
            }
        }
#pragma unroll
        for (int mi = 0; mi < 4; mi++) {
            int mt = mhalf * 4 + mi;
#pragma unroll
            for (int ni = 0; ni < 2; ni++) {
                int col = (nhalf * 2 + ni) * 16 + ln15;
                float bias = bk1[col];
#pragma unroll
                for (int r = 0; r < 4; r++) {
                    int q = mt * 16 + quad * 4 + r;
                    int l = t0 - 2 + q;
                    float v = acc[mi][ni][r] + bias;
                    v = v > 0.f ? v : __expf(v) - 1.f;
                    s1[q * SSTR + col] = (l >= 0 && l < LL) ? f2bf(v) : (short)0;
                }
            }
        }
    }
    __syncthreads();   // s1 ready; sEmb now dead -> reuse as B2 double-buffer

    // ---- phase 2: conv2. wave = 4 mt x 4 nt; B staged via LDS dbuf ----
    short* bbuf = sEmb;
    f32x4 acc2[4][4];
#pragma unroll
    for (int mi = 0; mi < 4; mi++)
#pragma unroll
        for (int ni = 0; ni < 4; ni++) acc2[mi][ni] = (f32x4){0.f, 0.f, 0.f, 0.f};
    int ch0 = t * 8;            // thread's two 16B chunks of the 8 KB (4096-short) tile
    int ch1 = 2048 + t * 8;
    short8 r0 = *(const short8*)&Bswz2[ch0];
    short8 r1 = *(const short8*)&Bswz2[ch1];
    for (int kb = 0; kb < 10; kb++) {
        int bo = (kb & 1) * 4096;
        *(short8*)&bbuf[bo + ch0] = r0;
        *(short8*)&bbuf[bo + ch1] = r1;
        __syncthreads();        // stage(kb) visible; prev readers done
        if (kb < 9) {           // prefetch kb+1 (overlaps MFMAs below)
            r0 = *(const short8*)&Bswz2[(kb + 1) * 4096 + ch0];
            r1 = *(const short8*)&Bswz2[(kb + 1) * 4096 + ch1];
        }
        int koff = kb * 32 + quad * 8;
        int kk = koff >> 6, i0 = koff & 63;
        short8 a[4], bb[4];
#pragma unroll
        for (int mi = 0; mi < 4; mi++) {
            int arow = (mhalf * 4 + mi) * 16 + ln15 + kk;
            a[mi] = *(const short8*)&s1[arow * SSTR + i0];
        }
#pragma unroll
        for (int ni = 0; ni < 4; ni++)
            bb[ni] = *(const short8*)&bbuf[bo + ((nhalf * 4 + ni) * 64 + lane) * 8];
#pragma unroll
        for (int mi = 0; mi < 4; mi++)
#pragma unroll
            for (int ni = 0; ni < 4; ni++)
                acc2[mi][ni] = __builtin_amdgcn_mfma_f32_16x16x32_bf16(a[mi], bb[ni], acc2[mi][ni], 0, 0, 0);
    }

    // ---- epilogue: bias, elu, masked max over rows, one atomic per (col, mhalf) ----
#pragma unroll
    for (int ni = 0; ni < 4; ni++) {
        int col = (nhalf * 4 + ni) * 16 + ln15;
        float bias = bk2[col];
        float mx = -1e30f;
#pragma unroll
        for (int mi = 0; mi < 4; mi++) {
#pragma unroll
            for (int r = 0; r < 4; r++) {
                int p = (mhalf * 4 + mi) * 16 + quad * 4 + r;
                float v = acc2[mi][ni][r] + bias;
                v = v > 0.f ? v : __expf(v) - 1.f;
                if (p < TL && t0 + p < LL) mx = fmaxf(mx, v);
            }
        }
        mx = fmaxf(mx, __shfl_xor(mx, 16, 64));
        mx = fmaxf(mx, __shfl_xor(mx, 32, 64));
        if (quad == 0) atomicMaxFloat(&pmax[b * 128 + col], mx);
    }
}

// ---------------- protein FC ----------------
__global__ void k_prot_fc(const float* pmax, const float* Wp, const float* bp, float* prot) {
    int idx = blockIdx.x * 256 + threadIdx.x;   // NB*256
    if (idx >= NB * 256) return;
    int g = idx >> 8, o = idx & 255;
    float acc = bp[o];
#pragma unroll 8
    for (int i = 0; i < 128; i++) acc += pmax[g * 128 + i] * Wp[i * 256 + o];
    prot[idx] = acc > 0.f ? acc : 0.f;
}

// ---------------- head MLP ----------------
__global__ void k_head(const float* drug, const float* prot, const float* Wf1, const float* bf1,
                       const float* Wf2, const float* bf2, const float* Wo, const float* bo,
                       float* out) {
    __shared__ float in[512];
    __shared__ float hh[128];
    __shared__ float h2s[64];
    int g = blockIdx.x, t = threadIdx.x;   // 128 threads
    in[t] = drug[g * 256 + t];
    in[128 + t] = drug[g * 256 + 128 + t];
    in[256 + t] = prot[g * 256 + t];
    in[384 + t] = prot[g * 256 + 128 + t];
    __syncthreads();
    float acc = bf1[t];
#pragma unroll 8
    for (int c = 0; c < 512; c++) acc += in[c] * Wf1[c * 128 + t];
    hh[t] = acc > 0.f ? acc : 0.f;
    __syncthreads();
    if (t < 64) {
        float a2 = bf2[t];
#pragma unroll 8
        for (int c = 0; c < 128; c++) a2 += hh[c] * Wf2[c * 64 + t];
        h2s[t] = a2 > 0.f ? a2 : 0.f;
    }
    __syncthreads();
    if (t == 0) {
        float o = bo[0];
#pragma unroll 8
        for (int c = 0; c < 64; c++) o += h2s[c] * Wo[c];
        out[g] = o;
    }
}

extern "C" void kernel_launch(void* const* d_in, const int* in_sizes, int n_in,
                              void* d_out, int out_size, void* d_ws, size_t ws_size,
                              hipStream_t stream) {
    (void)in_sizes; (void)n_in; (void)out_size; (void)ws_size;
    const float* x   = (const float*)d_in[0];
    const int* ei    = (const int*)d_in[1];
    const int* batch = (const int*)d_in[2];
    const int* seq   = (const int*)d_in[3];
    const float* W1  = (const float*)d_in[4];
    const float* a_s1 = (const float*)d_in[5];
    const float* a_d1 = (const float*)d_in[6];
    const float* b1  = (const float*)d_in[7];
    const float* W2  = (const float*)d_in[8];
    const float* a_s2 = (const float*)d_in[9];
    const float* a_d2 = (const float*)d_in[10];
    const float* b2  = (const float*)d_in[11];
    const float* Wd  = (const float*)d_in[12];
    const float* bd  = (const float*)d_in[13];
    const float* Pe  = (const float*)d_in[14];
    const float* K1  = (const float*)d_in[15];
    const float* bk1 = (const float*)d_in[16];
    const float* K2  = (const float*)d_in[17];
    const float* bk2 = (const float*)d_in[18];
    const float* Wp  = (const float*)d_in[19];
    const float* bp  = (const float*)d_in[20];
    const float* Wf1 = (const float*)d_in[21];
    const float* bf1 = (const float*)d_in[22];
    const float* Wf2 = (const float*)d_in[23];
    const float* bf2 = (const float*)d_in[24];
    const float* Wo  = (const float*)d_in[25];
    const float* bo  = (const float*)d_in[26];
    float* out = (float*)d_out;

    float* w = (float*)d_ws;
    float* h1   = w; w += NN * 128;
    float* g1   = w; w += NN * 128;
    float* h2   = w; w += NN * 128;
    float* g2   = w; w += NN * 128;
    float* as1  = w; w += NN * 2;
    float* ad1  = w; w += NN * 2;
    float* as2  = w; w += NN;
    float* ad2  = w; w += NN;
    float* sums = w; w += NG * 128;
    float* cnt  = w; w += NG;
    float* drug = w; w += NG * 256;
    float* prot = w; w += NB * 256;
    float* pmax = w; w += NB * 128;
    short* Bswz1 = (short*)w; w += 192 * 64 / 2;
    short* Bswz2 = (short*)w; w += 320 * 128 / 2;
    short* Bh2  = (short*)w; w += 128 * 128 / 2;
    short* Bl2  = (short*)w; w += 128 * 128 / 2;
    int* deg    = (int*)w; w += NN;
    int* cursor = (int*)w; w += NN;
    int* excl   = (int*)w; w += NN;
    int* part   = (int*)w; w += 128;
    int* rowptr = (int*)w; w += NN + 8;
    int* colidx = (int*)w; w += ETOT;

    // init + weight prep
    hipLaunchKernelGGL(k_init, dim3(256), dim3(256), 0, stream, deg, cursor, sums, cnt, pmax);
    hipLaunchKernelGGL(k_prep_w, dim3(160), dim3(256), 0, stream,
                       K1, K2, W2, Bswz1, Bswz2, Bh2, Bl2);

    // CSR build
    hipLaunchKernelGGL(k_count, dim3(ETOT / 256), dim3(256), 0, stream, ei, deg);
    hipLaunchKernelGGL(k_scan1, dim3(NN / 256), dim3(256), 0, stream, deg, excl, part);
    hipLaunchKernelGGL(k_scan2, dim3(1), dim3(128), 0, stream, part);
    hipLaunchKernelGGL(k_scan3, dim3(NN / 256), dim3(256), 0, stream, excl, part, rowptr);
    hipLaunchKernelGGL(k_scatter, dim3(ETOT / 256), dim3(256), 0, stream, ei, rowptr, cursor, colidx);

    // protein branch (MFMA)
    hipLaunchKernelGGL(k_protein, dim3(NB * NTILE), dim3(256), 0, stream,
                       seq, Pe, Bswz1, bk1, Bswz2, bk2, pmax);
    hipLaunchKernelGGL(k_prot_fc, dim3(NB), dim3(256), 0, stream, pmax, Wp, bp, prot);

    // GAT layer 1
    hipLaunchKernelGGL(k_gat1_hatt, dim3(NN * 128 / 256), dim3(256), 0, stream,
                       x, W1, a_s1, a_d1, h1, as1, ad1);
    hipLaunchKernelGGL(k_agg<2>, dim3(NN / 2), dim3(256), 0, stream,
                       rowptr, colidx, h1, as1, ad1, b1, g1);

    // GAT layer 2 (MFMA split-bf16 matmul + fused att dots)
    hipLaunchKernelGGL(k_gat2_mm, dim3(NN / 64), dim3(256), 0, stream,
                       g1, Bh2, Bl2, a_s2, a_d2, h2, as2, ad2);
    hipLaunchKernelGGL(k_agg<1>, dim3(NN / 2), dim3(256), 0, stream,
                       rowptr, colidx, h2, as2, ad2, b2, g2);

    // pool + drug FC
    hipLaunchKernelGGL(k_pool, dim3(NN / 96), dim3(128), 0, stream, g2, batch, sums, cnt);
    hipLaunchKernelGGL(k_drug_fc, dim3(NG), dim3(256), 0, stream, sums, cnt, Wd, bd, drug);

    // head
    hipLaunchKernelGGL(k_head, dim3(NG), dim3(128), 0, stream,
                       drug, prot, Wf1, bf1, Wf2, bf2, Wo, bo, out);
}